// Round 12
// baseline (553.375 us; speedup 1.0000x reference)
//
#include <hip/hip_runtime.h>
#include <hip/hip_bf16.h>
#include <math.h>

#define N_Q 2048
#define K_E 32
#define D_F 128
#define H_N 8
#define DH_N 16
#define EPS_F 1e-5f
#define NEGMAX -3.4028235e38f
#define EPB 8      // edges per edge-block

// R23: MFMA stage A abandoned for good (R22 moved the error to Output 1 --
// placement defect invisible to probes; pre-commitment binds). Base = R19
// edge (VALU stage A, compaction, g-major; best passing 436us) + R20's
// prep-fused k_qk (helped ~5us) + NEW: k_finish launch deleted via
// last-block-done reduction. Each active edge block: pbuf/mbuf store ->
// __syncthreads (vmcnt drained) -> threadfence (L2 wb) -> atomicAdd(cnt[n]).
// Block seeing old==nact-1 acquires and runs the finish phase in-block,
// R13-style over 512 threads (Ms/Dn -> combine+probs -> Wo 4-way split ->
// reduce+skip+write). cnt zeroed by k_qk each launch (stream order).

// ---------------------------------------------------------------------------
// Kernel A+B: query LN+Wq + per-n mask prep (blocks [0,N)) /
//             key Wk (blocks [N,2N)).
// Outputs packed float4: .xyz = vector part, .w = scalar part.
// ---------------------------------------------------------------------------
__global__ __launch_bounds__(128) void k_qk(
    const float* __restrict__ qs_in, const float* __restrict__ qv_in,
    const float* __restrict__ ks_in, const float* __restrict__ kv_in,
    const float* __restrict__ Wq_s, const float* __restrict__ Wq_v, const float* __restrict__ bq,
    const float* __restrict__ Wk_s, const float* __restrict__ Wk_v, const float* __restrict__ bk,
    const float* __restrict__ ln_gs, const float* __restrict__ ln_bs, const float* __restrict__ ln_gv,
    const int* __restrict__ mask,
    float4* __restrict__ q4, float4* __restrict__ k4,
    float* __restrict__ skip_s, float* __restrict__ skip_v,
    int* __restrict__ kidx, int* __restrict__ ucnt, int* __restrict__ cnt,
    float* __restrict__ attn_raw, float* __restrict__ mbuf)
{
    const int t = threadIdx.x;
    __shared__ __align__(16) float raw[D_F*3];
    __shared__ float4 sv[D_F];
    __shared__ float red[6];
    if (blockIdx.x < N_Q) {
        const int n = blockIdx.x;
        // ---- fused k_prep (wave 0 only) ----
        if (t < 64) {
            const int k = t & 31;
            int mk = (t < 32) ? mask[n*K_E + k] : 0;
            unsigned long long bal = __ballot(mk != 0);
            int u = (int)__popcll(bal);
            if (t < 32 && mk) {
                int pos = (int)__popcll(bal & ((1ull << k) - 1ull));
                kidx[n*K_E + pos] = k;
            }
            if (t == 0) { ucnt[n] = u; cnt[n] = 0; }
            if (mask[n*K_E + k] == 0) {
                int hb = (t >> 5) * 4;
                #pragma unroll
                for (int hh = 0; hh < 4; ++hh)
                    attn_raw[(size_t)(hb + hh)*(N_Q*K_E) + n*K_E + k] = NEGMAX;
            }
            int gU = (u + 7) >> 3;
            if (t < 16) {
                for (int g2 = gU; g2 < 4; ++g2)
                    mbuf[(n*4 + g2)*16 + t] = (t < 8) ? NEGMAX : 0.f;
            }
        }
        // ---- LN + Wq ----
        float sval = qs_in[n*D_F + t];
        float ssqp = 0.f;
        if (t < 96) {
            float4 rv = ((const float4*)(qv_in + (size_t)n*D_F*3))[t];
            ((float4*)raw)[t] = rv;
            ssqp = rv.x*rv.x + rv.y*rv.y + rv.z*rv.z + rv.w*rv.w;
        }
        float r0 = sval, r1 = sval*sval, r2 = ssqp;
        #pragma unroll
        for (int m = 1; m < 64; m <<= 1) {
            r0 += __shfl_xor(r0, m);
            r1 += __shfl_xor(r1, m);
            r2 += __shfl_xor(r2, m);
        }
        if ((t & 63) == 0) { int w = t >> 6; red[w*3+0]=r0; red[w*3+1]=r1; red[w*3+2]=r2; }
        __syncthreads();
        float tS = red[0]+red[3], tS2 = red[1]+red[4], tQ = red[2]+red[5];
        float mu = tS * (1.f/D_F);
        float var = fmaxf(tS2*(1.f/D_F) - mu*mu, 0.f);
        float rstd = rsqrtf(var + EPS_F);
        float rrms = rsqrtf(tQ*(1.f/D_F) + EPS_F);
        float a = (sval - mu)*rstd*ln_gs[t] + ln_bs[t];
        skip_s[n*D_F + t] = a;
        float gv = ln_gv[t];
        float b0 = raw[t*3+0]*rrms*gv;
        float b1 = raw[t*3+1]*rrms*gv;
        float b2 = raw[t*3+2]*rrms*gv;
        skip_v[(n*D_F + t)*3 + 0] = b0;
        skip_v[(n*D_F + t)*3 + 1] = b1;
        skip_v[(n*D_F + t)*3 + 2] = b2;
        sv[t] = make_float4(b0, b1, b2, a);
        __syncthreads();
        float acc = bq[t], a0 = 0.f, a1 = 0.f, a2 = 0.f;
        #pragma unroll 4
        for (int i = 0; i < D_F; ++i) {
            float4 p = sv[i];
            float ws = Wq_s[i*D_F + t];
            float wv = Wq_v[i*D_F + t];
            acc += p.w*ws; a0 += p.x*wv; a1 += p.y*wv; a2 += p.z*wv;
        }
        q4[n*D_F + t] = make_float4(a0, a1, a2, acc);
    } else {
        const int n = blockIdx.x - N_Q;
        float sval = ks_in[n*D_F + t];
        if (t < 96) ((float4*)raw)[t] = ((const float4*)(kv_in + (size_t)n*D_F*3))[t];
        __syncthreads();
        sv[t] = make_float4(raw[t*3+0], raw[t*3+1], raw[t*3+2], sval);
        __syncthreads();
        float acc = bk[t], a0 = 0.f, a1 = 0.f, a2 = 0.f;
        #pragma unroll 4
        for (int i = 0; i < D_F; ++i) {
            float4 p = sv[i];
            float ws = Wk_s[i*D_F + t];
            float wv = Wk_v[i*D_F + t];
            acc += p.w*ws; a0 += p.x*wv; a1 += p.y*wv; a2 += p.z*wv;
        }
        k4[n*D_F + t] = make_float4(a0, a1, a2, acc);
    }
}

// ---------------------------------------------------------------------------
// k_edge_flash: R19 pipeline on compacted slots (g-major) + in-kernel finish
// by the last-done block of each n.
// ---------------------------------------------------------------------------
__global__ __launch_bounds__(512, 6) void k_edge_flash(
    const float4* __restrict__ q4, const float4* __restrict__ k4,
    const float* __restrict__ eis, const float* __restrict__ eiv,
    const float* __restrict__ eemb,
    const int* __restrict__ knn,
    const int* __restrict__ kidx, const int* __restrict__ ucnt, int* __restrict__ cnt,
    const float* __restrict__ Wqk_s, const float* __restrict__ Wqk_v, const float* __restrict__ bqk,
    const float* __restrict__ Wdtp, const float* __restrict__ bdtp,
    const float* __restrict__ Wagv_s, const float* __restrict__ bagv, const float* __restrict__ Wagv_v,
    const float* __restrict__ Wattn, const float* __restrict__ lna_g, const float* __restrict__ lna_b,
    const float* __restrict__ Wval_s, const float* __restrict__ Wval_v, const float* __restrict__ bval,
    const float* __restrict__ Wo_s, const float* __restrict__ Wo_v, const float* __restrict__ bo,
    const float* __restrict__ skip_s, const float* __restrict__ skip_v,
    float4* __restrict__ pbuf, float* __restrict__ mbuf, float* __restrict__ attn_raw,
    float* __restrict__ out0, float* __restrict__ out1)
{
    const int n = blockIdx.x & (N_Q - 1);   // g-major: XCD = n%8 per plane
    const int g = blockIdx.x >> 11;
    const int base = n*K_E;
    const int u = ucnt[n];
    if ((g << 3) >= u) return;         // dead group: mbuf prefilled in k_qk

    const int t = threadIdx.x;
    const int s = t >> 7, c = t & 127, h = (t >> 4) & 7, o = t & 15;
    const int rot2 = h * 2;

    __shared__ float4 ch[EPB*256];     // 32 KB (stage-A ee aliased here; finish xsh)
    __shared__ float4 w4[EPB*128];     // 16 KB; reused as partial-combine stage
    __shared__ float  afeat[EPB*8*17]; // 4.25 KB: 16 feats + logit col 16
    __shared__ float  mred[16];        // Mg[8], deng[8]
    __shared__ float  MsDn[16];        // finish: M*[8], den[8]
    __shared__ int    lastFlag;

    // stage A: ee gather (compacted, transposed, aliased into ch) + w GEMM
    {
        float* ee = (float*)ch;        // [128][8] floats = 4 KB
        {
            int idx = t; int m = idx & 7, i = idx >> 3;
            int jj = (g<<3) + m; jj = (jj < u) ? jj : (u-1);
            int e = base + kidx[base + jj];
            ee[i*EPB+m] = eemb[(size_t)e*D_F + i];
        }
        {
            int idx = t + 512; int m = idx & 7, i = idx >> 3;
            int jj = (g<<3) + m; jj = (jj < u) ? jj : (u-1);
            int e = base + kidx[base + jj];
            ee[i*EPB+m] = eemb[(size_t)e*D_F + i];
        }
        __syncthreads();
        float acc[EPB];
        float b = bdtp[t];
        #pragma unroll
        for (int m = 0; m < EPB; ++m) acc[m] = b;
        #pragma unroll 2
        for (int i = 0; i < D_F; ++i) {
            float wv = Wdtp[i*512 + t];
            #pragma unroll
            for (int m = 0; m < EPB; ++m) acc[m] += ee[i*EPB+m]*wv;
        }
        __syncthreads();               // all ee reads done -> ch reusable
        float* w4f = (float*)w4;
        const int chn = t & 127, sel = t >> 7;
        #pragma unroll
        for (int m = 0; m < EPB; ++m)
            w4f[(m*128 + chn)*4 + sel] = acc[m];
    }

    const int mA = s, mB = s + 4;
    int jA = (g<<3) + mA; jA = (jA < u) ? jA : (u-1);
    int jB = (g<<3) + mB; jB = (jB < u) ? jB : (u-1);
    const int eA = base + kidx[base + jA];
    const int eB = base + kidx[base + jB];

    const float esA = eis[eA], esB = eis[eB];
    const float evAx = eiv[eA*3+0], evAy = eiv[eA*3+1], evAz = eiv[eA*3+2];
    const float evBx = eiv[eB*3+0], evBy = eiv[eB*3+1], evBz = eiv[eB*3+2];

    // B1: dtp1 straight from global
    {
        float4 q  = q4[(size_t)n*D_F + c];
        float4 kA = k4[(size_t)knn[eA]*D_F + c];
        float4 kB = k4[(size_t)knn[eB]*D_F + c];
        const int hp = c >> 5, jc = c & 31;
        const int pos0 = hp*32 + ((jc + 2*hp) & 31);
        const int pos1 = (hp+4)*32 + ((jc + 2*(hp+4)) & 31);
        ch[mA*256 + pos0] = make_float4(q.w*kA.x, q.w*kA.y, q.w*kA.z, q.w*kA.w);
        ch[mA*256 + pos1] = make_float4(kA.w*q.x, kA.w*q.y, kA.w*q.z,
                                        q.x*kA.x + q.y*kA.y + q.z*kA.z);
        ch[mB*256 + pos0] = make_float4(q.w*kB.x, q.w*kB.y, q.w*kB.z, q.w*kB.w);
        ch[mB*256 + pos1] = make_float4(kB.w*q.x, kB.w*q.y, kB.w*q.z,
                                        q.x*kB.x + q.y*kB.y + q.z*kB.z);
    }
    __syncthreads();

    const int chA = mA*256 + h*32, chB = mB*256 + h*32;

    // B2: Wqk
    float pAs, pA0, pA1, pA2, pBs, pB0, pB1, pB2;
    {
        const float bqk_r = bqk[o];
        pAs = bqk_r; pA0 = 0.f; pA1 = 0.f; pA2 = 0.f;
        pBs = bqk_r; pB0 = 0.f; pB1 = 0.f; pB2 = 0.f;
        #pragma unroll 4
        for (int i = 0; i < 32; ++i) {
            int ph = (i + rot2) & 31;
            float4 cA = ch[chA + ph];
            float4 cB = ch[chB + ph];
            float ws = Wqk_s[i*16 + o];
            float wv = Wqk_v[i*16 + o];
            pAs += cA.w*ws; pA0 += cA.x*wv; pA1 += cA.y*wv; pA2 += cA.z*wv;
            pBs += cB.w*ws; pB0 += cB.x*wv; pB1 += cB.y*wv; pB2 += cB.z*wv;
        }
    }
    __syncthreads();

    const int posA = h*32 + ((o + rot2) & 31);
    const int posB = h*32 + ((o + 16 + rot2) & 31);

    // B3: dtp2 (weighted)
    {
        float4 wA = w4[mA*128 + c];
        float4 wB = w4[mB*128 + c];
        ch[mA*256 + posA] = make_float4(pAs*evAx*wA.z, pAs*evAy*wA.z, pAs*evAz*wA.z, pAs*esA*wA.x);
        float dA = pA0*evAx + pA1*evAy + pA2*evAz;
        ch[mA*256 + posB] = make_float4(esA*pA0*wA.w, esA*pA1*wA.w, esA*pA2*wA.w, dA*wA.y);
        ch[mB*256 + posA] = make_float4(pBs*evBx*wB.z, pBs*evBy*wB.z, pBs*evBz*wB.z, pBs*esB*wB.x);
        float dB = pB0*evBx + pB1*evBy + pB2*evBz;
        ch[mB*256 + posB] = make_float4(esB*pB0*wB.w, esB*pB1*wB.w, esB*pB2*wB.w, dB*wB.y);
    }
    __syncthreads();

    // B4: Wagv
    float gtA, vlA, vA0, vA1, vA2, gtB, vlB, vB0, vB1, vB2;
    {
        const float bag0 = bagv[h*48 + o];
        const float bag1 = bagv[h*48 + 16 + o];
        const float bag2 = bagv[h*48 + 32 + o];
        float atA = bag0, atB = bag0;
        gtA = bag1; vlA = bag2; vA0 = 0.f; vA1 = 0.f; vA2 = 0.f;
        gtB = bag1; vlB = bag2; vB0 = 0.f; vB1 = 0.f; vB2 = 0.f;
        #pragma unroll 4
        for (int i = 0; i < 32; ++i) {
            int ph = (i + rot2) & 31;
            float4 cA = ch[chA + ph];
            float4 cB = ch[chB + ph];
            const float* wrow = &Wagv_s[(h*32+i)*48];
            float w0 = wrow[o], w1 = wrow[16+o], w2 = wrow[32+o];
            float wv = Wagv_v[(h*32+i)*16 + o];
            atA += cA.w*w0; gtA += cA.w*w1; vlA += cA.w*w2;
            vA0 += cA.x*wv; vA1 += cA.y*wv; vA2 += cA.z*wv;
            atB += cB.w*w0; gtB += cB.w*w1; vlB += cB.w*w2;
            vB0 += cB.x*wv; vB1 += cB.y*wv; vB2 += cB.z*wv;
        }
        afeat[(mA*8 + h)*17 + o] = atA;
        afeat[(mB*8 + h)*17 + o] = atB;
    }
    __syncthreads();

    // B5: logits (wave 0: 8 slots x 8 heads) + group max/den via shuffles
    if (t < EPB*H_N) {
        int m2 = t >> 3, h2 = t & 7;
        const float* afr = &afeat[(m2*8 + h2)*17];
        float mu = 0.f;
        #pragma unroll 4
        for (int d2 = 0; d2 < DH_N; ++d2) mu += afr[d2];
        mu *= (1.f/DH_N);
        float var = 0.f;
        #pragma unroll 4
        for (int d2 = 0; d2 < DH_N; ++d2) { float dd = afr[d2]-mu; var += dd*dd; }
        var *= (1.f/DH_N);
        float rstd = rsqrtf(var + EPS_F);
        float logit = 0.f;
        #pragma unroll 4
        for (int d2 = 0; d2 < DH_N; ++d2) {
            float xn = (afr[d2]-mu)*rstd*lna_g[d2] + lna_b[d2];
            logit += xn*Wattn[d2];
        }
        int jj = (g<<3) + m2;
        bool vok = jj < u;
        if (vok) {
            int kor = kidx[base + jj];
            attn_raw[h2*(N_Q*K_E) + n*K_E + kor] = logit;
        } else {
            logit = NEGMAX;            // clamped duplicate slot: exact 0 weight
        }
        afeat[(m2*8 + h2)*17 + 16] = logit;
        float mx = logit;
        mx = fmaxf(mx, __shfl_xor(mx, 8));
        mx = fmaxf(mx, __shfl_xor(mx, 16));
        mx = fmaxf(mx, __shfl_xor(mx, 32));
        float ex = expf(logit - mx);
        ex += __shfl_xor(ex, 8);
        ex += __shfl_xor(ex, 16);
        ex += __shfl_xor(ex, 32);
        if (m2 == 0) { mred[h2] = mx; mred[8 + h2] = ex; }
    }
    // gating (register-only, all threads)
    float sactA = vlA / (1.f + expf(-vlA));
    float gA = 1.f / (1.f + expf(-gtA));
    float qA0 = vA0*gA, qA1 = vA1*gA, qA2 = vA2*gA;
    float sactB = vlB / (1.f + expf(-vlB));
    float gB = 1.f / (1.f + expf(-gtB));
    float qB0 = vB0*gB, qB1 = vB1*gB, qB2 = vB2*gB;

    // B6: dtp3
    {
        ch[mA*256 + posA] = make_float4(sactA*evAx, sactA*evAy, sactA*evAz, sactA*esA);
        float dA = qA0*evAx + qA1*evAy + qA2*evAz;
        ch[mA*256 + posB] = make_float4(esA*qA0, esA*qA1, esA*qA2, dA);
        ch[mB*256 + posA] = make_float4(sactB*evBx, sactB*evBy, sactB*evBz, sactB*esB);
        float dB = qB0*evBx + qB1*evBy + qB2*evBz;
        ch[mB*256 + posB] = make_float4(esB*qB0, esB*qB1, esB*qB2, dB);
    }
    __syncthreads();

    // B7: Wval -> registers, weight by exp(logit - Mg), stage partial in w4
    {
        const float bval_r = bval[o];
        float vsA = bval_r, uA0 = 0.f, uA1 = 0.f, uA2 = 0.f;
        float vsB = bval_r, uB0 = 0.f, uB1 = 0.f, uB2 = 0.f;
        #pragma unroll 4
        for (int i = 0; i < 32; ++i) {
            int ph = (i + rot2) & 31;
            float4 cA = ch[chA + ph];
            float4 cB = ch[chB + ph];
            float ws = Wval_s[i*16 + o];
            float wv = Wval_v[i*16 + o];
            vsA += cA.w*ws; uA0 += cA.x*wv; uA1 += cA.y*wv; uA2 += cA.z*wv;
            vsB += cB.w*ws; uB0 += cB.x*wv; uB1 += cB.y*wv; uB2 += cB.z*wv;
        }
        float lA = afeat[(mA*8 + h)*17 + 16];
        float lB = afeat[(mB*8 + h)*17 + 16];
        float Mg = mred[h];
        float wgA = expf(lA - Mg);     // invalid slot: exp(-inf)=0 exact
        float wgB = expf(lB - Mg);
        w4[s*128 + c] = make_float4(wgA*uA0 + wgB*uB0, wgA*uA1 + wgB*uB1,
                                    wgA*uA2 + wgB*uB2, wgA*vsA + wgB*vsB);
    }
    __syncthreads();

    // tail: combine 4 s-slots -> one partial float4 per channel; emit Mg/deng
    if (t < 128) {
        float4 a = w4[t], b4 = w4[128 + t], c4 = w4[256 + t], d4 = w4[384 + t];
        pbuf[((size_t)(n*4 + g))*D_F + t] =
            make_float4(a.x + b4.x + c4.x + d4.x, a.y + b4.y + c4.y + d4.y,
                        a.z + b4.z + c4.z + d4.z, a.w + b4.w + c4.w + d4.w);
    } else if (t < 144) {
        mbuf[(n*4 + g)*16 + (t - 128)] = mred[t - 128];
    }
    __syncthreads();                   // all waves' global writes drained (vmcnt)

    // ---- last-block-done handoff ----
    if (t == 0) {
        __threadfence();               // release: this block's pbuf/mbuf visible
        int nact = (u + 7) >> 3;
        int old = atomicAdd(&cnt[n], 1);
        int last = (old == nact - 1);
        if (last) __threadfence();     // acquire: invalidate caches for peer data
        lastFlag = last;
    }
    __syncthreads();
    if (!lastFlag) return;

    // ---- finish phase (one block per n) ----
    // F1: per-head global max/den from 4 group partials
    if (t < 32) {
        int h3 = t >> 2, g3 = t & 3;
        float mg = mbuf[(n*4 + g3)*16 + h3];
        float dg = mbuf[(n*4 + g3)*16 + 8 + h3];
        float mx = mg;
        mx = fmaxf(mx, __shfl_xor(mx, 1));
        mx = fmaxf(mx, __shfl_xor(mx, 2));
        float dsc = dg * expf(mg - mx);   // dead group: 0 * 0
        dsc += __shfl_xor(dsc, 1);
        dsc += __shfl_xor(dsc, 2);
        if (g3 == 0) { MsDn[h3] = mx; MsDn[8 + h3] = dsc; }
    }
    __syncthreads();
    // F2: combine group partials -> xsh (ch[1024..1151]); probs in place
    if (t < 128) {
        int hh = t >> 4, oo = t & 15;
        const float M = MsDn[hh];
        const float rden = 1.f / MsDn[8 + hh];
        float4 a4 = make_float4(0.f, 0.f, 0.f, 0.f);
        #pragma unroll
        for (int gg = 0; gg < 4; ++gg) {
            float mg = mbuf[(n*4 + gg)*16 + hh];
            if (mg > -1e37f) {         // skip dead groups (pbuf unwritten)
                float4 pv = pbuf[((size_t)(n*4 + gg))*D_F + t];
                float sf = expf(mg - M) * rden;
                a4.x += pv.x*sf; a4.y += pv.y*sf; a4.z += pv.z*sf; a4.w += pv.w*sf;
            }
        }
        ch[1024 + t] = a4;
        #pragma unroll
        for (int kk = 0; kk < 2; ++kk) {
            size_t idx = (size_t)hh*(N_Q*K_E) + (size_t)n*K_E + (oo + kk*16);
            attn_raw[idx] = expf(attn_raw[idx] - M) * rden;
        }
    }
    __syncthreads();
    // F3: Wo partial GEMM (each s-slot takes 32 of 128 inputs)
    {
        float po_s = 0.f, po0 = 0.f, po1 = 0.f, po2 = 0.f;
        const int ib = s*32;
        #pragma unroll 4
        for (int ii = 0; ii < 32; ++ii) {
            int i = ib + ii;
            float4 x = ch[1024 + i];
            float ws = Wo_s[i*D_F + c];
            float wv = Wo_v[i*D_F + c];
            po_s += x.w*ws; po0 += x.x*wv; po1 += x.y*wv; po2 += x.z*wv;
        }
        w4[s*128 + c] = make_float4(po0, po1, po2, po_s);
    }
    __syncthreads();
    // F4: reduce, bias, skip, write
    if (t < 128) {
        float4 a = w4[t], b4 = w4[128 + t], c4 = w4[256 + t], d4 = w4[384 + t];
        float os = a.w + b4.w + c4.w + d4.w + bo[t];
        float o0 = a.x + b4.x + c4.x + d4.x;
        float o1 = a.y + b4.y + c4.y + d4.y;
        float o2 = a.z + b4.z + c4.z + d4.z;
        out0[n*D_F + t] = os + skip_s[n*D_F + t];
        out1[(n*D_F + t)*3 + 0] = o0 + skip_v[(n*D_F + t)*3 + 0];
        out1[(n*D_F + t)*3 + 1] = o1 + skip_v[(n*D_F + t)*3 + 1];
        out1[(n*D_F + t)*3 + 2] = o2 + skip_v[(n*D_F + t)*3 + 2];
    }
}

// ---------------------------------------------------------------------------
extern "C" void kernel_launch(void* const* d_in, const int* in_sizes, int n_in,
                              void* d_out, int out_size, void* d_ws, size_t ws_size,
                              hipStream_t stream)
{
    (void)in_sizes; (void)n_in; (void)out_size; (void)ws_size;

    const float* query_s = (const float*)d_in[0];
    const float* query_v = (const float*)d_in[1];
    const float* key_s   = (const float*)d_in[2];
    const float* key_v   = (const float*)d_in[3];
    const float* eis     = (const float*)d_in[4];
    const float* eiv     = (const float*)d_in[5];
    const float* eemb    = (const float*)d_in[6];
    const int*   mask    = (const int*)d_in[7];
    const int*   knn     = (const int*)d_in[8];
    const float* Wq_s    = (const float*)d_in[9];
    const float* Wq_v    = (const float*)d_in[10];
    const float* bq      = (const float*)d_in[11];
    const float* Wk_s    = (const float*)d_in[12];
    const float* Wk_v    = (const float*)d_in[13];
    const float* bk      = (const float*)d_in[14];
    const float* Wqk_s   = (const float*)d_in[15];
    const float* Wqk_v   = (const float*)d_in[16];
    const float* bqk     = (const float*)d_in[17];
    const float* Wdtp    = (const float*)d_in[18];
    const float* bdtp    = (const float*)d_in[19];
    const float* Wagv_s  = (const float*)d_in[20];
    const float* bagv    = (const float*)d_in[21];
    const float* Wagv_v  = (const float*)d_in[22];
    const float* Wattn   = (const float*)d_in[23];
    const float* Wval_s  = (const float*)d_in[24];
    const float* Wval_v  = (const float*)d_in[25];
    const float* bval    = (const float*)d_in[26];
    const float* Wo_s    = (const float*)d_in[27];
    const float* Wo_v    = (const float*)d_in[28];
    const float* bo      = (const float*)d_in[29];
    const float* ln_gs   = (const float*)d_in[30];
    const float* ln_bs   = (const float*)d_in[31];
    const float* ln_gv   = (const float*)d_in[32];
    const float* lna_g   = (const float*)d_in[33];
    const float* lna_b   = (const float*)d_in[34];

    float* out      = (float*)d_out;
    float* out_s    = out;
    float* out_v    = out + N_Q*D_F;
    float* out_attn = out + N_Q*D_F*4;

    float* ws = (float*)d_ws;
    float4* q4     = (float4*)ws;                      // N*128 f4 = 4 MB
    float4* k4     = q4 + N_Q*D_F;                     // 4 MB
    float*  skip_s = (float*)(k4 + N_Q*D_F);           // 1 MB
    float*  skip_v = skip_s + N_Q*D_F;                 // 3 MB
    float4* pbuf   = (float4*)(skip_v + N_Q*D_F*3);    // N*4*128 f4 = 16 MB
    float*  mbuf   = (float*)(pbuf + N_Q*4*D_F);       // N*4*16 f = 512 KB
    int*    kidx   = (int*)(mbuf + N_Q*4*16);          // N*K ints = 256 KB
    int*    ucnt   = kidx + N_Q*K_E;                   // N ints
    int*    cnt    = ucnt + N_Q;                       // N ints

    hipLaunchKernelGGL(k_qk, dim3(2*N_Q), dim3(D_F), 0, stream,
                       query_s, query_v, key_s, key_v,
                       Wq_s, Wq_v, bq, Wk_s, Wk_v, bk,
                       ln_gs, ln_bs, ln_gv, mask,
                       q4, k4, skip_s, skip_v,
                       kidx, ucnt, cnt, out_attn, mbuf);
    hipLaunchKernelGGL(k_edge_flash, dim3(N_Q*K_E/EPB), dim3(512), 0, stream,
                       q4, k4, eis, eiv, eemb, knn, kidx, ucnt, cnt,
                       Wqk_s, Wqk_v, bqk, Wdtp, bdtp,
                       Wagv_s, bagv, Wagv_v, Wattn, lna_g, lna_b,
                       Wval_s, Wval_v, bval,
                       Wo_s, Wo_v, bo, skip_s, skip_v,
                       pbuf, mbuf, out_attn, out_s, out_v);
}

// Round 13
// 431.803 us; speedup vs baseline: 1.2815x; 1.2815x over previous
//
#include <hip/hip_runtime.h>
#include <hip/hip_bf16.h>
#include <math.h>

#define N_Q 2048
#define K_E 32
#define D_F 128
#define H_N 8
#define DH_N 16
#define EPS_F 1e-5f
#define NEGMAX -3.4028235e38f
#define EPB 8      // edges per edge-block

// R24: revert R23's fused finish (per-block __threadfence = L2 writeback per
// 5100 blocks -> edge 293->441us; launches are cheaper fences on MI355X).
// Base = R19 (436us best). Three safe cuts:
//  (1) stage-A LDS reads explicit b128 (8 scalar b32 -> 2 float4 per iter,
//      broadcast conflict-free; ~768 fewer issues/thread).
//  (2) k_prep fused into k_qk query blocks (R20's proven-good half, ~7us).
//  (3) k_finish: 2 n per block -- each Wo weight load feeds both n's FMAs
//      (weight-load issue halved; grid 1024). Same math, same order.
// Edge pipeline otherwise byte-identical to R19.

// ---------------------------------------------------------------------------
// Kernel A+B: query LN+Wq + per-n mask prep (blocks [0,N)) /
//             key Wk (blocks [N,2N)).
// Outputs packed float4: .xyz = vector part, .w = scalar part.
// ---------------------------------------------------------------------------
__global__ __launch_bounds__(128) void k_qk(
    const float* __restrict__ qs_in, const float* __restrict__ qv_in,
    const float* __restrict__ ks_in, const float* __restrict__ kv_in,
    const float* __restrict__ Wq_s, const float* __restrict__ Wq_v, const float* __restrict__ bq,
    const float* __restrict__ Wk_s, const float* __restrict__ Wk_v, const float* __restrict__ bk,
    const float* __restrict__ ln_gs, const float* __restrict__ ln_bs, const float* __restrict__ ln_gv,
    const int* __restrict__ mask,
    float4* __restrict__ q4, float4* __restrict__ k4,
    float* __restrict__ skip_s, float* __restrict__ skip_v,
    int* __restrict__ kidx, int* __restrict__ ucnt,
    float* __restrict__ attn_raw, float* __restrict__ mbuf)
{
    const int t = threadIdx.x;
    __shared__ __align__(16) float raw[D_F*3];
    __shared__ float4 sv[D_F];
    __shared__ float red[6];
    if (blockIdx.x < N_Q) {
        const int n = blockIdx.x;
        // ---- fused k_prep (wave 0 only) ----
        if (t < 64) {
            const int k = t & 31;
            int mk = (t < 32) ? mask[n*K_E + k] : 0;
            unsigned long long bal = __ballot(mk != 0);
            int u = (int)__popcll(bal);
            if (t < 32 && mk) {
                int pos = (int)__popcll(bal & ((1ull << k) - 1ull));
                kidx[n*K_E + pos] = k;
            }
            if (t == 0) ucnt[n] = u;
            if (mask[n*K_E + k] == 0) {
                int hb = (t >> 5) * 4;
                #pragma unroll
                for (int hh = 0; hh < 4; ++hh)
                    attn_raw[(size_t)(hb + hh)*(N_Q*K_E) + n*K_E + k] = NEGMAX;
            }
            int gU = (u + 7) >> 3;
            if (t < 16) {
                for (int g2 = gU; g2 < 4; ++g2)
                    mbuf[(n*4 + g2)*16 + t] = (t < 8) ? NEGMAX : 0.f;
            }
        }
        // ---- LN + Wq ----
        float sval = qs_in[n*D_F + t];
        float ssqp = 0.f;
        if (t < 96) {
            float4 rv = ((const float4*)(qv_in + (size_t)n*D_F*3))[t];
            ((float4*)raw)[t] = rv;
            ssqp = rv.x*rv.x + rv.y*rv.y + rv.z*rv.z + rv.w*rv.w;
        }
        float r0 = sval, r1 = sval*sval, r2 = ssqp;
        #pragma unroll
        for (int m = 1; m < 64; m <<= 1) {
            r0 += __shfl_xor(r0, m);
            r1 += __shfl_xor(r1, m);
            r2 += __shfl_xor(r2, m);
        }
        if ((t & 63) == 0) { int w = t >> 6; red[w*3+0]=r0; red[w*3+1]=r1; red[w*3+2]=r2; }
        __syncthreads();
        float tS = red[0]+red[3], tS2 = red[1]+red[4], tQ = red[2]+red[5];
        float mu = tS * (1.f/D_F);
        float var = fmaxf(tS2*(1.f/D_F) - mu*mu, 0.f);
        float rstd = rsqrtf(var + EPS_F);
        float rrms = rsqrtf(tQ*(1.f/D_F) + EPS_F);
        float a = (sval - mu)*rstd*ln_gs[t] + ln_bs[t];
        skip_s[n*D_F + t] = a;
        float gv = ln_gv[t];
        float b0 = raw[t*3+0]*rrms*gv;
        float b1 = raw[t*3+1]*rrms*gv;
        float b2 = raw[t*3+2]*rrms*gv;
        skip_v[(n*D_F + t)*3 + 0] = b0;
        skip_v[(n*D_F + t)*3 + 1] = b1;
        skip_v[(n*D_F + t)*3 + 2] = b2;
        sv[t] = make_float4(b0, b1, b2, a);
        __syncthreads();
        float acc = bq[t], a0 = 0.f, a1 = 0.f, a2 = 0.f;
        #pragma unroll 4
        for (int i = 0; i < D_F; ++i) {
            float4 p = sv[i];
            float ws = Wq_s[i*D_F + t];
            float wv = Wq_v[i*D_F + t];
            acc += p.w*ws; a0 += p.x*wv; a1 += p.y*wv; a2 += p.z*wv;
        }
        q4[n*D_F + t] = make_float4(a0, a1, a2, acc);
    } else {
        const int n = blockIdx.x - N_Q;
        float sval = ks_in[n*D_F + t];
        if (t < 96) ((float4*)raw)[t] = ((const float4*)(kv_in + (size_t)n*D_F*3))[t];
        __syncthreads();
        sv[t] = make_float4(raw[t*3+0], raw[t*3+1], raw[t*3+2], sval);
        __syncthreads();
        float acc = bk[t], a0 = 0.f, a1 = 0.f, a2 = 0.f;
        #pragma unroll 4
        for (int i = 0; i < D_F; ++i) {
            float4 p = sv[i];
            float ws = Wk_s[i*D_F + t];
            float wv = Wk_v[i*D_F + t];
            acc += p.w*ws; a0 += p.x*wv; a1 += p.y*wv; a2 += p.z*wv;
        }
        k4[n*D_F + t] = make_float4(a0, a1, a2, acc);
    }
}

// ---------------------------------------------------------------------------
// k_edge_flash: R19 pipeline on COMPACTED edge slots, g-major block mapping.
// Stage-A GEMM reads ee via explicit b128 (broadcast, conflict-free).
// ---------------------------------------------------------------------------
__global__ __launch_bounds__(512, 6) void k_edge_flash(
    const float4* __restrict__ q4, const float4* __restrict__ k4,
    const float* __restrict__ eis, const float* __restrict__ eiv,
    const float* __restrict__ eemb,
    const int* __restrict__ knn,
    const int* __restrict__ kidx, const int* __restrict__ ucnt,
    const float* __restrict__ Wqk_s, const float* __restrict__ Wqk_v, const float* __restrict__ bqk,
    const float* __restrict__ Wdtp, const float* __restrict__ bdtp,
    const float* __restrict__ Wagv_s, const float* __restrict__ bagv, const float* __restrict__ Wagv_v,
    const float* __restrict__ Wattn, const float* __restrict__ lna_g, const float* __restrict__ lna_b,
    const float* __restrict__ Wval_s, const float* __restrict__ Wval_v, const float* __restrict__ bval,
    float4* __restrict__ pbuf, float* __restrict__ mbuf, float* __restrict__ attn_raw)
{
    const int n = blockIdx.x & (N_Q - 1);   // g-major: XCD = n%8 per plane
    const int g = blockIdx.x >> 11;
    const int base = n*K_E;
    const int u = ucnt[n];
    if ((g << 3) >= u) return;         // dead group: mbuf prefilled in k_qk

    const int t = threadIdx.x;
    const int s = t >> 7, c = t & 127, h = (t >> 4) & 7, o = t & 15;
    const int rot2 = h * 2;

    __shared__ float4 ch[EPB*256];     // 32 KB (stage-A ee aliased here)
    __shared__ float4 w4[EPB*128];     // 16 KB; reused as partial-combine stage
    __shared__ float  afeat[EPB*8*17]; // 4.25 KB: 16 feats + logit col 16
    __shared__ float  mred[16];        // Mg[8], deng[8]

    // stage A: ee gather (compacted, transposed, aliased into ch) + w GEMM
    {
        float* ee = (float*)ch;        // [128][8] floats = 4 KB
        {
            int idx = t; int m = idx & 7, i = idx >> 3;
            int jj = (g<<3) + m; jj = (jj < u) ? jj : (u-1);
            int e = base + kidx[base + jj];
            ee[i*EPB+m] = eemb[(size_t)e*D_F + i];
        }
        {
            int idx = t + 512; int m = idx & 7, i = idx >> 3;
            int jj = (g<<3) + m; jj = (jj < u) ? jj : (u-1);
            int e = base + kidx[base + jj];
            ee[i*EPB+m] = eemb[(size_t)e*D_F + i];
        }
        __syncthreads();
        float acc[EPB];
        float b = bdtp[t];
        #pragma unroll
        for (int m = 0; m < EPB; ++m) acc[m] = b;
        const float4* ee4 = (const float4*)ch;
        #pragma unroll 2
        for (int i = 0; i < D_F; ++i) {
            float wv = Wdtp[i*512 + t];
            float4 e0 = ee4[i*2];      // ds_read_b128, same addr all lanes
            float4 e1 = ee4[i*2+1];    //   -> broadcast, conflict-free
            acc[0] += e0.x*wv; acc[1] += e0.y*wv; acc[2] += e0.z*wv; acc[3] += e0.w*wv;
            acc[4] += e1.x*wv; acc[5] += e1.y*wv; acc[6] += e1.z*wv; acc[7] += e1.w*wv;
        }
        __syncthreads();               // all ee reads done -> ch reusable
        float* w4f = (float*)w4;
        const int chn = t & 127, sel = t >> 7;
        #pragma unroll
        for (int m = 0; m < EPB; ++m)
            w4f[(m*128 + chn)*4 + sel] = acc[m];
    }

    const int mA = s, mB = s + 4;
    int jA = (g<<3) + mA; jA = (jA < u) ? jA : (u-1);
    int jB = (g<<3) + mB; jB = (jB < u) ? jB : (u-1);
    const int eA = base + kidx[base + jA];
    const int eB = base + kidx[base + jB];

    const float esA = eis[eA], esB = eis[eB];
    const float evAx = eiv[eA*3+0], evAy = eiv[eA*3+1], evAz = eiv[eA*3+2];
    const float evBx = eiv[eB*3+0], evBy = eiv[eB*3+1], evBz = eiv[eB*3+2];

    // B1: dtp1 straight from global
    {
        float4 q  = q4[(size_t)n*D_F + c];
        float4 kA = k4[(size_t)knn[eA]*D_F + c];
        float4 kB = k4[(size_t)knn[eB]*D_F + c];
        const int hp = c >> 5, jc = c & 31;
        const int pos0 = hp*32 + ((jc + 2*hp) & 31);
        const int pos1 = (hp+4)*32 + ((jc + 2*(hp+4)) & 31);
        ch[mA*256 + pos0] = make_float4(q.w*kA.x, q.w*kA.y, q.w*kA.z, q.w*kA.w);
        ch[mA*256 + pos1] = make_float4(kA.w*q.x, kA.w*q.y, kA.w*q.z,
                                        q.x*kA.x + q.y*kA.y + q.z*kA.z);
        ch[mB*256 + pos0] = make_float4(q.w*kB.x, q.w*kB.y, q.w*kB.z, q.w*kB.w);
        ch[mB*256 + pos1] = make_float4(kB.w*q.x, kB.w*q.y, kB.w*q.z,
                                        q.x*kB.x + q.y*kB.y + q.z*kB.z);
    }
    __syncthreads();

    const int chA = mA*256 + h*32, chB = mB*256 + h*32;

    // B2: Wqk
    float pAs, pA0, pA1, pA2, pBs, pB0, pB1, pB2;
    {
        const float bqk_r = bqk[o];
        pAs = bqk_r; pA0 = 0.f; pA1 = 0.f; pA2 = 0.f;
        pBs = bqk_r; pB0 = 0.f; pB1 = 0.f; pB2 = 0.f;
        #pragma unroll 4
        for (int i = 0; i < 32; ++i) {
            int ph = (i + rot2) & 31;
            float4 cA = ch[chA + ph];
            float4 cB = ch[chB + ph];
            float ws = Wqk_s[i*16 + o];
            float wv = Wqk_v[i*16 + o];
            pAs += cA.w*ws; pA0 += cA.x*wv; pA1 += cA.y*wv; pA2 += cA.z*wv;
            pBs += cB.w*ws; pB0 += cB.x*wv; pB1 += cB.y*wv; pB2 += cB.z*wv;
        }
    }
    __syncthreads();

    const int posA = h*32 + ((o + rot2) & 31);
    const int posB = h*32 + ((o + 16 + rot2) & 31);

    // B3: dtp2 (weighted)
    {
        float4 wA = w4[mA*128 + c];
        float4 wB = w4[mB*128 + c];
        ch[mA*256 + posA] = make_float4(pAs*evAx*wA.z, pAs*evAy*wA.z, pAs*evAz*wA.z, pAs*esA*wA.x);
        float dA = pA0*evAx + pA1*evAy + pA2*evAz;
        ch[mA*256 + posB] = make_float4(esA*pA0*wA.w, esA*pA1*wA.w, esA*pA2*wA.w, dA*wA.y);
        ch[mB*256 + posA] = make_float4(pBs*evBx*wB.z, pBs*evBy*wB.z, pBs*evBz*wB.z, pBs*esB*wB.x);
        float dB = pB0*evBx + pB1*evBy + pB2*evBz;
        ch[mB*256 + posB] = make_float4(esB*pB0*wB.w, esB*pB1*wB.w, esB*pB2*wB.w, dB*wB.y);
    }
    __syncthreads();

    // B4: Wagv
    float gtA, vlA, vA0, vA1, vA2, gtB, vlB, vB0, vB1, vB2;
    {
        const float bag0 = bagv[h*48 + o];
        const float bag1 = bagv[h*48 + 16 + o];
        const float bag2 = bagv[h*48 + 32 + o];
        float atA = bag0, atB = bag0;
        gtA = bag1; vlA = bag2; vA0 = 0.f; vA1 = 0.f; vA2 = 0.f;
        gtB = bag1; vlB = bag2; vB0 = 0.f; vB1 = 0.f; vB2 = 0.f;
        #pragma unroll 4
        for (int i = 0; i < 32; ++i) {
            int ph = (i + rot2) & 31;
            float4 cA = ch[chA + ph];
            float4 cB = ch[chB + ph];
            const float* wrow = &Wagv_s[(h*32+i)*48];
            float w0 = wrow[o], w1 = wrow[16+o], w2 = wrow[32+o];
            float wv = Wagv_v[(h*32+i)*16 + o];
            atA += cA.w*w0; gtA += cA.w*w1; vlA += cA.w*w2;
            vA0 += cA.x*wv; vA1 += cA.y*wv; vA2 += cA.z*wv;
            atB += cB.w*w0; gtB += cB.w*w1; vlB += cB.w*w2;
            vB0 += cB.x*wv; vB1 += cB.y*wv; vB2 += cB.z*wv;
        }
        afeat[(mA*8 + h)*17 + o] = atA;
        afeat[(mB*8 + h)*17 + o] = atB;
    }
    __syncthreads();

    // B5: logits (wave 0: 8 slots x 8 heads) + group max/den via shuffles
    if (t < EPB*H_N) {
        int m2 = t >> 3, h2 = t & 7;
        const float* afr = &afeat[(m2*8 + h2)*17];
        float mu = 0.f;
        #pragma unroll 4
        for (int d2 = 0; d2 < DH_N; ++d2) mu += afr[d2];
        mu *= (1.f/DH_N);
        float var = 0.f;
        #pragma unroll 4
        for (int d2 = 0; d2 < DH_N; ++d2) { float dd = afr[d2]-mu; var += dd*dd; }
        var *= (1.f/DH_N);
        float rstd = rsqrtf(var + EPS_F);
        float logit = 0.f;
        #pragma unroll 4
        for (int d2 = 0; d2 < DH_N; ++d2) {
            float xn = (afr[d2]-mu)*rstd*lna_g[d2] + lna_b[d2];
            logit += xn*Wattn[d2];
        }
        int jj = (g<<3) + m2;
        bool vok = jj < u;
        if (vok) {
            int kor = kidx[base + jj];
            attn_raw[h2*(N_Q*K_E) + n*K_E + kor] = logit;
        } else {
            logit = NEGMAX;            // clamped duplicate slot: exact 0 weight
        }
        afeat[(m2*8 + h2)*17 + 16] = logit;
        float mx = logit;
        mx = fmaxf(mx, __shfl_xor(mx, 8));
        mx = fmaxf(mx, __shfl_xor(mx, 16));
        mx = fmaxf(mx, __shfl_xor(mx, 32));
        float ex = expf(logit - mx);
        ex += __shfl_xor(ex, 8);
        ex += __shfl_xor(ex, 16);
        ex += __shfl_xor(ex, 32);
        if (m2 == 0) { mred[h2] = mx; mred[8 + h2] = ex; }
    }
    // gating (register-only, all threads)
    float sactA = vlA / (1.f + expf(-vlA));
    float gA = 1.f / (1.f + expf(-gtA));
    float qA0 = vA0*gA, qA1 = vA1*gA, qA2 = vA2*gA;
    float sactB = vlB / (1.f + expf(-vlB));
    float gB = 1.f / (1.f + expf(-gtB));
    float qB0 = vB0*gB, qB1 = vB1*gB, qB2 = vB2*gB;

    // B6: dtp3
    {
        ch[mA*256 + posA] = make_float4(sactA*evAx, sactA*evAy, sactA*evAz, sactA*esA);
        float dA = qA0*evAx + qA1*evAy + qA2*evAz;
        ch[mA*256 + posB] = make_float4(esA*qA0, esA*qA1, esA*qA2, dA);
        ch[mB*256 + posA] = make_float4(sactB*evBx, sactB*evBy, sactB*evBz, sactB*esB);
        float dB = qB0*evBx + qB1*evBy + qB2*evBz;
        ch[mB*256 + posB] = make_float4(esB*qB0, esB*qB1, esB*qB2, dB);
    }
    __syncthreads();

    // B7: Wval -> registers, weight by exp(logit - Mg), stage partial in w4
    {
        const float bval_r = bval[o];
        float vsA = bval_r, uA0 = 0.f, uA1 = 0.f, uA2 = 0.f;
        float vsB = bval_r, uB0 = 0.f, uB1 = 0.f, uB2 = 0.f;
        #pragma unroll 4
        for (int i = 0; i < 32; ++i) {
            int ph = (i + rot2) & 31;
            float4 cA = ch[chA + ph];
            float4 cB = ch[chB + ph];
            float ws = Wval_s[i*16 + o];
            float wv = Wval_v[i*16 + o];
            vsA += cA.w*ws; uA0 += cA.x*wv; uA1 += cA.y*wv; uA2 += cA.z*wv;
            vsB += cB.w*ws; uB0 += cB.x*wv; uB1 += cB.y*wv; uB2 += cB.z*wv;
        }
        float lA = afeat[(mA*8 + h)*17 + 16];
        float lB = afeat[(mB*8 + h)*17 + 16];
        float Mg = mred[h];
        float wgA = expf(lA - Mg);     // invalid slot: exp(-inf)=0 exact
        float wgB = expf(lB - Mg);
        w4[s*128 + c] = make_float4(wgA*uA0 + wgB*uB0, wgA*uA1 + wgB*uB1,
                                    wgA*uA2 + wgB*uB2, wgA*vsA + wgB*vsB);
    }
    __syncthreads();

    // tail: combine 4 s-slots -> one partial float4 per channel; emit Mg/deng
    if (t < 128) {
        float4 a = w4[t], b4 = w4[128 + t], c4 = w4[256 + t], d4 = w4[384 + t];
        pbuf[((size_t)(n*4 + g))*D_F + t] =
            make_float4(a.x + b4.x + c4.x + d4.x, a.y + b4.y + c4.y + d4.y,
                        a.z + b4.z + c4.z + d4.z, a.w + b4.w + c4.w + d4.w);
    } else if (t < 144) {
        mbuf[(n*4 + g)*16 + (t - 128)] = mred[t - 128];
    }
}

// ---------------------------------------------------------------------------
// k_finish: TWO n per block (128 threads). Each Wo weight element is loaded
// once and feeds both n's FMAs. Same math/order as R19's k_finish.
// ---------------------------------------------------------------------------
__global__ __launch_bounds__(128) void k_finish(
    const float4* __restrict__ pbuf, const float* __restrict__ mbuf,
    float* __restrict__ attn_out,     // in: raw logits, out: probabilities
    const float* __restrict__ skip_s, const float* __restrict__ skip_v,
    const float* __restrict__ Wo_s, const float* __restrict__ Wo_v, const float* __restrict__ bo,
    float* __restrict__ out0, float* __restrict__ out1)
{
    const int n0 = blockIdx.x*2, t = threadIdx.x;
    __shared__ float MsDn[32];            // [which][M*8 | Dn*8]
    __shared__ float4 xsh[2*D_F];
    // F1: per-head global max/den for both n (t<64, single wave)
    if (t < 64) {
        int which = t >> 5, tt = t & 31;
        int nn = n0 + which;
        int h3 = tt >> 2, g3 = tt & 3;
        float mg = mbuf[(nn*4 + g3)*16 + h3];
        float dg = mbuf[(nn*4 + g3)*16 + 8 + h3];
        float mx = mg;
        mx = fmaxf(mx, __shfl_xor(mx, 1));
        mx = fmaxf(mx, __shfl_xor(mx, 2));
        float dsc = dg * expf(mg - mx);   // dead group: 0 * 0
        dsc += __shfl_xor(dsc, 1);
        dsc += __shfl_xor(dsc, 2);
        if (g3 == 0) { MsDn[which*16 + h3] = mx; MsDn[which*16 + 8 + h3] = dsc; }
    }
    __syncthreads();
    const int h = t >> 4, o = t & 15;
    // F2: combine group partials for both n; probs in place
    #pragma unroll
    for (int w = 0; w < 2; ++w) {
        int nn = n0 + w;
        const float M = MsDn[w*16 + h];
        const float rden = 1.f / MsDn[w*16 + 8 + h];
        float4 acc = make_float4(0.f, 0.f, 0.f, 0.f);
        #pragma unroll
        for (int gg = 0; gg < 4; ++gg) {
            float mg = mbuf[(nn*4 + gg)*16 + h];
            if (mg > -1e37f) {            // skip dead groups (pbuf unwritten)
                float4 pv = pbuf[((size_t)(nn*4 + gg))*D_F + t];
                float sf = expf(mg - M) * rden;
                acc.x += pv.x*sf; acc.y += pv.y*sf; acc.z += pv.z*sf; acc.w += pv.w*sf;
            }
        }
        xsh[w*D_F + t] = acc;
        #pragma unroll
        for (int kk = 0; kk < 2; ++kk) {
            size_t idx = (size_t)h*(N_Q*K_E) + (size_t)nn*K_E + (o + kk*16);
            attn_out[idx] = expf(attn_out[idx] - M) * rden;
        }
    }
    __syncthreads();
    // F3: Wo GEMM, one weight load -> both n
    float s0 = bo[t], a00 = 0.f, a01 = 0.f, a02 = 0.f;
    float s1 = s0,    a10 = 0.f, a11 = 0.f, a12 = 0.f;
    #pragma unroll 4
    for (int i = 0; i < D_F; ++i) {
        float ws = Wo_s[i*D_F + t];
        float wv = Wo_v[i*D_F + t];
        float4 x0 = xsh[i];
        float4 x1 = xsh[D_F + i];
        s0 += x0.w*ws; a00 += x0.x*wv; a01 += x0.y*wv; a02 += x0.z*wv;
        s1 += x1.w*ws; a10 += x1.x*wv; a11 += x1.y*wv; a12 += x1.z*wv;
    }
    out0[n0*D_F + t] = s0 + skip_s[n0*D_F + t];
    out1[(n0*D_F + t)*3 + 0] = a00 + skip_v[(n0*D_F + t)*3 + 0];
    out1[(n0*D_F + t)*3 + 1] = a01 + skip_v[(n0*D_F + t)*3 + 1];
    out1[(n0*D_F + t)*3 + 2] = a02 + skip_v[(n0*D_F + t)*3 + 2];
    const int n1 = n0 + 1;
    out0[n1*D_F + t] = s1 + skip_s[n1*D_F + t];
    out1[(n1*D_F + t)*3 + 0] = a10 + skip_v[(n1*D_F + t)*3 + 0];
    out1[(n1*D_F + t)*3 + 1] = a11 + skip_v[(n1*D_F + t)*3 + 1];
    out1[(n1*D_F + t)*3 + 2] = a12 + skip_v[(n1*D_F + t)*3 + 2];
}

// ---------------------------------------------------------------------------
extern "C" void kernel_launch(void* const* d_in, const int* in_sizes, int n_in,
                              void* d_out, int out_size, void* d_ws, size_t ws_size,
                              hipStream_t stream)
{
    (void)in_sizes; (void)n_in; (void)out_size; (void)ws_size;

    const float* query_s = (const float*)d_in[0];
    const float* query_v = (const float*)d_in[1];
    const float* key_s   = (const float*)d_in[2];
    const float* key_v   = (const float*)d_in[3];
    const float* eis     = (const float*)d_in[4];
    const float* eiv     = (const float*)d_in[5];
    const float* eemb    = (const float*)d_in[6];
    const int*   mask    = (const int*)d_in[7];
    const int*   knn     = (const int*)d_in[8];
    const float* Wq_s    = (const float*)d_in[9];
    const float* Wq_v    = (const float*)d_in[10];
    const float* bq      = (const float*)d_in[11];
    const float* Wk_s    = (const float*)d_in[12];
    const float* Wk_v    = (const float*)d_in[13];
    const float* bk      = (const float*)d_in[14];
    const float* Wqk_s   = (const float*)d_in[15];
    const float* Wqk_v   = (const float*)d_in[16];
    const float* bqk     = (const float*)d_in[17];
    const float* Wdtp    = (const float*)d_in[18];
    const float* bdtp    = (const float*)d_in[19];
    const float* Wagv_s  = (const float*)d_in[20];
    const float* bagv    = (const float*)d_in[21];
    const float* Wagv_v  = (const float*)d_in[22];
    const float* Wattn   = (const float*)d_in[23];
    const float* Wval_s  = (const float*)d_in[24];
    const float* Wval_v  = (const float*)d_in[25];
    const float* bval    = (const float*)d_in[26];
    const float* Wo_s    = (const float*)d_in[27];
    const float* Wo_v    = (const float*)d_in[28];
    const float* bo      = (const float*)d_in[29];
    const float* ln_gs   = (const float*)d_in[30];
    const float* ln_bs   = (const float*)d_in[31];
    const float* ln_gv   = (const float*)d_in[32];
    const float* lna_g   = (const float*)d_in[33];
    const float* lna_b   = (const float*)d_in[34];

    float* out      = (float*)d_out;
    float* out_s    = out;
    float* out_v    = out + N_Q*D_F;
    float* out_attn = out + N_Q*D_F*4;

    float* ws = (float*)d_ws;
    float4* q4     = (float4*)ws;                      // N*128 f4 = 4 MB
    float4* k4     = q4 + N_Q*D_F;                     // 4 MB
    float*  skip_s = (float*)(k4 + N_Q*D_F);           // 1 MB
    float*  skip_v = skip_s + N_Q*D_F;                 // 3 MB
    float4* pbuf   = (float4*)(skip_v + N_Q*D_F*3);    // N*4*128 f4 = 16 MB
    float*  mbuf   = (float*)(pbuf + N_Q*4*D_F);       // N*4*16 f = 512 KB
    int*    kidx   = (int*)(mbuf + N_Q*4*16);          // N*K ints = 256 KB
    int*    ucnt   = kidx + N_Q*K_E;                   // N ints

    hipLaunchKernelGGL(k_qk, dim3(2*N_Q), dim3(D_F), 0, stream,
                       query_s, query_v, key_s, key_v,
                       Wq_s, Wq_v, bq, Wk_s, Wk_v, bk,
                       ln_gs, ln_bs, ln_gv, mask,
                       q4, k4, skip_s, skip_v,
                       kidx, ucnt, out_attn, mbuf);
    hipLaunchKernelGGL(k_edge_flash, dim3(N_Q*K_E/EPB), dim3(512), 0, stream,
                       q4, k4, eis, eiv, eemb, knn, kidx, ucnt,
                       Wqk_s, Wqk_v, bqk, Wdtp, bdtp,
                       Wagv_s, bagv, Wagv_v, Wattn, lna_g, lna_b,
                       Wval_s, Wval_v, bval,
                       pbuf, mbuf, out_attn);
    hipLaunchKernelGGL(k_finish, dim3(N_Q/2), dim3(D_F), 0, stream,
                       pbuf, mbuf, out_attn, skip_s, skip_v, Wo_s, Wo_v, bo,
                       out_s, out_v);
}

// Round 14
// 418.134 us; speedup vs baseline: 1.3234x; 1.0327x over previous
//
#include <hip/hip_runtime.h>
#include <hip/hip_bf16.h>
#include <math.h>

#define N_Q 2048
#define K_E 32
#define D_F 128
#define H_N 8
#define DH_N 16
#define EPS_F 1e-5f
#define NEGMAX -3.4028235e38f
#define EPB 8      // edges per edge-block

typedef __attribute__((ext_vector_type(2))) float v2f;

// R25: packed-FP32 experiment on R24 (431.8us best). All hot FMA loops
// rewritten as v2f (<2 x float>) so clang emits v_pk_fma_f32 (VOP3P, 2
// FMA/lane/inst, gfx90a+). Pairing is within-register: every consumer reads
// float4 from ds_read_b128, so (x,y) and (z,w) are adjacent VGPR pairs;
// weight splats fold into op_sel. Per-component accumulation chains are
// UNCHANGED -> bit-identical absmax. Stage A 8->4 pk/iter, B2/B7 8->4,
// B4 12->6, k_qk 8->4, k_finish F3 16->8. If CDNA4 packed fp32 is
// full-rate: edge ~-12%; if double-pumped: issue relief only (~neutral).

// ---------------------------------------------------------------------------
// Kernel A+B: query LN+Wq + per-n mask prep (blocks [0,N)) /
//             key Wk (blocks [N,2N)).
// Outputs packed float4: .xyz = vector part, .w = scalar part.
// ---------------------------------------------------------------------------
__global__ __launch_bounds__(128) void k_qk(
    const float* __restrict__ qs_in, const float* __restrict__ qv_in,
    const float* __restrict__ ks_in, const float* __restrict__ kv_in,
    const float* __restrict__ Wq_s, const float* __restrict__ Wq_v, const float* __restrict__ bq,
    const float* __restrict__ Wk_s, const float* __restrict__ Wk_v, const float* __restrict__ bk,
    const float* __restrict__ ln_gs, const float* __restrict__ ln_bs, const float* __restrict__ ln_gv,
    const int* __restrict__ mask,
    float4* __restrict__ q4, float4* __restrict__ k4,
    float* __restrict__ skip_s, float* __restrict__ skip_v,
    int* __restrict__ kidx, int* __restrict__ ucnt,
    float* __restrict__ attn_raw, float* __restrict__ mbuf)
{
    const int t = threadIdx.x;
    __shared__ __align__(16) float raw[D_F*3];
    __shared__ float4 sv[D_F];
    __shared__ float red[6];
    if (blockIdx.x < N_Q) {
        const int n = blockIdx.x;
        // ---- fused k_prep (wave 0 only) ----
        if (t < 64) {
            const int k = t & 31;
            int mk = (t < 32) ? mask[n*K_E + k] : 0;
            unsigned long long bal = __ballot(mk != 0);
            int u = (int)__popcll(bal);
            if (t < 32 && mk) {
                int pos = (int)__popcll(bal & ((1ull << k) - 1ull));
                kidx[n*K_E + pos] = k;
            }
            if (t == 0) ucnt[n] = u;
            if (mask[n*K_E + k] == 0) {
                int hb = (t >> 5) * 4;
                #pragma unroll
                for (int hh = 0; hh < 4; ++hh)
                    attn_raw[(size_t)(hb + hh)*(N_Q*K_E) + n*K_E + k] = NEGMAX;
            }
            int gU = (u + 7) >> 3;
            if (t < 16) {
                for (int g2 = gU; g2 < 4; ++g2)
                    mbuf[(n*4 + g2)*16 + t] = (t < 8) ? NEGMAX : 0.f;
            }
        }
        // ---- LN + Wq ----
        float sval = qs_in[n*D_F + t];
        float ssqp = 0.f;
        if (t < 96) {
            float4 rv = ((const float4*)(qv_in + (size_t)n*D_F*3))[t];
            ((float4*)raw)[t] = rv;
            ssqp = rv.x*rv.x + rv.y*rv.y + rv.z*rv.z + rv.w*rv.w;
        }
        float r0 = sval, r1 = sval*sval, r2 = ssqp;
        #pragma unroll
        for (int m = 1; m < 64; m <<= 1) {
            r0 += __shfl_xor(r0, m);
            r1 += __shfl_xor(r1, m);
            r2 += __shfl_xor(r2, m);
        }
        if ((t & 63) == 0) { int w = t >> 6; red[w*3+0]=r0; red[w*3+1]=r1; red[w*3+2]=r2; }
        __syncthreads();
        float tS = red[0]+red[3], tS2 = red[1]+red[4], tQ = red[2]+red[5];
        float mu = tS * (1.f/D_F);
        float var = fmaxf(tS2*(1.f/D_F) - mu*mu, 0.f);
        float rstd = rsqrtf(var + EPS_F);
        float rrms = rsqrtf(tQ*(1.f/D_F) + EPS_F);
        float a = (sval - mu)*rstd*ln_gs[t] + ln_bs[t];
        skip_s[n*D_F + t] = a;
        float gv = ln_gv[t];
        float b0 = raw[t*3+0]*rrms*gv;
        float b1 = raw[t*3+1]*rrms*gv;
        float b2 = raw[t*3+2]*rrms*gv;
        skip_v[(n*D_F + t)*3 + 0] = b0;
        skip_v[(n*D_F + t)*3 + 1] = b1;
        skip_v[(n*D_F + t)*3 + 2] = b2;
        sv[t] = make_float4(b0, b1, b2, a);
        __syncthreads();
        v2f a01 = (v2f){0.f, 0.f};
        v2f a2s = (v2f){0.f, bq[t]};
        #pragma unroll 4
        for (int i = 0; i < D_F; ++i) {
            float4 p = sv[i];
            float ws = Wq_s[i*D_F + t];
            float wv = Wq_v[i*D_F + t];
            a01 += (v2f){p.x, p.y} * (v2f){wv, wv};
            a2s += (v2f){p.z, p.w} * (v2f){wv, ws};
        }
        q4[n*D_F + t] = make_float4(a01.x, a01.y, a2s.x, a2s.y);
    } else {
        const int n = blockIdx.x - N_Q;
        float sval = ks_in[n*D_F + t];
        if (t < 96) ((float4*)raw)[t] = ((const float4*)(kv_in + (size_t)n*D_F*3))[t];
        __syncthreads();
        sv[t] = make_float4(raw[t*3+0], raw[t*3+1], raw[t*3+2], sval);
        __syncthreads();
        v2f a01 = (v2f){0.f, 0.f};
        v2f a2s = (v2f){0.f, bk[t]};
        #pragma unroll 4
        for (int i = 0; i < D_F; ++i) {
            float4 p = sv[i];
            float ws = Wk_s[i*D_F + t];
            float wv = Wk_v[i*D_F + t];
            a01 += (v2f){p.x, p.y} * (v2f){wv, wv};
            a2s += (v2f){p.z, p.w} * (v2f){wv, ws};
        }
        k4[n*D_F + t] = make_float4(a01.x, a01.y, a2s.x, a2s.y);
    }
}

// ---------------------------------------------------------------------------
// k_edge_flash: R19 pipeline on COMPACTED edge slots, g-major block mapping,
// packed-FP32 accumulation in stage A / B2 / B4 / B7.
// ---------------------------------------------------------------------------
__global__ __launch_bounds__(512, 6) void k_edge_flash(
    const float4* __restrict__ q4, const float4* __restrict__ k4,
    const float* __restrict__ eis, const float* __restrict__ eiv,
    const float* __restrict__ eemb,
    const int* __restrict__ knn,
    const int* __restrict__ kidx, const int* __restrict__ ucnt,
    const float* __restrict__ Wqk_s, const float* __restrict__ Wqk_v, const float* __restrict__ bqk,
    const float* __restrict__ Wdtp, const float* __restrict__ bdtp,
    const float* __restrict__ Wagv_s, const float* __restrict__ bagv, const float* __restrict__ Wagv_v,
    const float* __restrict__ Wattn, const float* __restrict__ lna_g, const float* __restrict__ lna_b,
    const float* __restrict__ Wval_s, const float* __restrict__ Wval_v, const float* __restrict__ bval,
    float4* __restrict__ pbuf, float* __restrict__ mbuf, float* __restrict__ attn_raw)
{
    const int n = blockIdx.x & (N_Q - 1);   // g-major: XCD = n%8 per plane
    const int g = blockIdx.x >> 11;
    const int base = n*K_E;
    const int u = ucnt[n];
    if ((g << 3) >= u) return;         // dead group: mbuf prefilled in k_qk

    const int t = threadIdx.x;
    const int s = t >> 7, c = t & 127, h = (t >> 4) & 7, o = t & 15;
    const int rot2 = h * 2;

    __shared__ float4 ch[EPB*256];     // 32 KB (stage-A ee aliased here)
    __shared__ float4 w4[EPB*128];     // 16 KB; reused as partial-combine stage
    __shared__ float  afeat[EPB*8*17]; // 4.25 KB: 16 feats + logit col 16
    __shared__ float  mred[16];        // Mg[8], deng[8]

    // stage A: ee gather (compacted, transposed, aliased into ch) + w GEMM
    {
        float* ee = (float*)ch;        // [128][8] floats = 4 KB
        {
            int idx = t; int m = idx & 7, i = idx >> 3;
            int jj = (g<<3) + m; jj = (jj < u) ? jj : (u-1);
            int e = base + kidx[base + jj];
            ee[i*EPB+m] = eemb[(size_t)e*D_F + i];
        }
        {
            int idx = t + 512; int m = idx & 7, i = idx >> 3;
            int jj = (g<<3) + m; jj = (jj < u) ? jj : (u-1);
            int e = base + kidx[base + jj];
            ee[i*EPB+m] = eemb[(size_t)e*D_F + i];
        }
        __syncthreads();
        float b = bdtp[t];
        v2f acc2[4];
        #pragma unroll
        for (int j = 0; j < 4; ++j) acc2[j] = (v2f){b, b};
        const float4* ee4 = (const float4*)ch;
        #pragma unroll 2
        for (int i = 0; i < D_F; ++i) {
            float wv = Wdtp[i*512 + t];
            v2f wv2 = (v2f){wv, wv};
            float4 e0 = ee4[i*2];      // ds_read_b128, broadcast conflict-free
            float4 e1 = ee4[i*2+1];
            acc2[0] += (v2f){e0.x, e0.y} * wv2;
            acc2[1] += (v2f){e0.z, e0.w} * wv2;
            acc2[2] += (v2f){e1.x, e1.y} * wv2;
            acc2[3] += (v2f){e1.z, e1.w} * wv2;
        }
        __syncthreads();               // all ee reads done -> ch reusable
        float* w4f = (float*)w4;
        const int chn = t & 127, sel = t >> 7;
        #pragma unroll
        for (int m = 0; m < EPB; ++m)
            w4f[(m*128 + chn)*4 + sel] = acc2[m >> 1][m & 1];
    }

    const int mA = s, mB = s + 4;
    int jA = (g<<3) + mA; jA = (jA < u) ? jA : (u-1);
    int jB = (g<<3) + mB; jB = (jB < u) ? jB : (u-1);
    const int eA = base + kidx[base + jA];
    const int eB = base + kidx[base + jB];

    const float esA = eis[eA], esB = eis[eB];
    const float evAx = eiv[eA*3+0], evAy = eiv[eA*3+1], evAz = eiv[eA*3+2];
    const float evBx = eiv[eB*3+0], evBy = eiv[eB*3+1], evBz = eiv[eB*3+2];

    // B1: dtp1 straight from global
    {
        float4 q  = q4[(size_t)n*D_F + c];
        float4 kA = k4[(size_t)knn[eA]*D_F + c];
        float4 kB = k4[(size_t)knn[eB]*D_F + c];
        const int hp = c >> 5, jc = c & 31;
        const int pos0 = hp*32 + ((jc + 2*hp) & 31);
        const int pos1 = (hp+4)*32 + ((jc + 2*(hp+4)) & 31);
        ch[mA*256 + pos0] = make_float4(q.w*kA.x, q.w*kA.y, q.w*kA.z, q.w*kA.w);
        ch[mA*256 + pos1] = make_float4(kA.w*q.x, kA.w*q.y, kA.w*q.z,
                                        q.x*kA.x + q.y*kA.y + q.z*kA.z);
        ch[mB*256 + pos0] = make_float4(q.w*kB.x, q.w*kB.y, q.w*kB.z, q.w*kB.w);
        ch[mB*256 + pos1] = make_float4(kB.w*q.x, kB.w*q.y, kB.w*q.z,
                                        q.x*kB.x + q.y*kB.y + q.z*kB.z);
    }
    __syncthreads();

    const int chA = mA*256 + h*32, chB = mB*256 + h*32;

    // B2: Wqk — packed: (p0,p1)+=(c.x,c.y)*(wv,wv); (p2,ps)+=(c.z,c.w)*(wv,ws)
    float pAs, pA0, pA1, pA2, pBs, pB0, pB1, pB2;
    {
        const float bqk_r = bqk[o];
        v2f a01A = (v2f){0.f, 0.f}, a2sA = (v2f){0.f, bqk_r};
        v2f a01B = (v2f){0.f, 0.f}, a2sB = (v2f){0.f, bqk_r};
        #pragma unroll 4
        for (int i = 0; i < 32; ++i) {
            int ph = (i + rot2) & 31;
            float4 cA = ch[chA + ph];
            float4 cB = ch[chB + ph];
            float ws = Wqk_s[i*16 + o];
            float wv = Wqk_v[i*16 + o];
            v2f wvv = (v2f){wv, wv};
            v2f wvs = (v2f){wv, ws};
            a01A += (v2f){cA.x, cA.y} * wvv;
            a2sA += (v2f){cA.z, cA.w} * wvs;
            a01B += (v2f){cB.x, cB.y} * wvv;
            a2sB += (v2f){cB.z, cB.w} * wvs;
        }
        pA0 = a01A.x; pA1 = a01A.y; pA2 = a2sA.x; pAs = a2sA.y;
        pB0 = a01B.x; pB1 = a01B.y; pB2 = a2sB.x; pBs = a2sB.y;
    }
    __syncthreads();

    const int posA = h*32 + ((o + rot2) & 31);
    const int posB = h*32 + ((o + 16 + rot2) & 31);

    // B3: dtp2 (weighted)
    {
        float4 wA = w4[mA*128 + c];
        float4 wB = w4[mB*128 + c];
        ch[mA*256 + posA] = make_float4(pAs*evAx*wA.z, pAs*evAy*wA.z, pAs*evAz*wA.z, pAs*esA*wA.x);
        float dA = pA0*evAx + pA1*evAy + pA2*evAz;
        ch[mA*256 + posB] = make_float4(esA*pA0*wA.w, esA*pA1*wA.w, esA*pA2*wA.w, dA*wA.y);
        ch[mB*256 + posA] = make_float4(pBs*evBx*wB.z, pBs*evBy*wB.z, pBs*evBz*wB.z, pBs*esB*wB.x);
        float dB = pB0*evBx + pB1*evBy + pB2*evBz;
        ch[mB*256 + posB] = make_float4(esB*pB0*wB.w, esB*pB1*wB.w, esB*pB2*wB.w, dB*wB.y);
    }
    __syncthreads();

    // B4: Wagv — packed: (v0,v1)+=(c.x,c.y)*(wv,wv); (v2,at)+=(c.z,c.w)*(wv,w0);
    //            (gt,vl)+=(c.w,c.w)*(w1,w2)
    float gtA, vlA, vA0, vA1, vA2, gtB, vlB, vB0, vB1, vB2;
    {
        const float bag0 = bagv[h*48 + o];
        const float bag1 = bagv[h*48 + 16 + o];
        const float bag2 = bagv[h*48 + 32 + o];
        v2f v01A = (v2f){0.f, 0.f}, v2atA = (v2f){0.f, bag0}, gtvlA = (v2f){bag1, bag2};
        v2f v01B = (v2f){0.f, 0.f}, v2atB = (v2f){0.f, bag0}, gtvlB = (v2f){bag1, bag2};
        #pragma unroll 4
        for (int i = 0; i < 32; ++i) {
            int ph = (i + rot2) & 31;
            float4 cA = ch[chA + ph];
            float4 cB = ch[chB + ph];
            const float* wrow = &Wagv_s[(h*32+i)*48];
            float w0 = wrow[o], w1 = wrow[16+o], w2 = wrow[32+o];
            float wv = Wagv_v[(h*32+i)*16 + o];
            v2f wvv = (v2f){wv, wv};
            v2f wv0 = (v2f){wv, w0};
            v2f w12 = (v2f){w1, w2};
            v01A  += (v2f){cA.x, cA.y} * wvv;
            v2atA += (v2f){cA.z, cA.w} * wv0;
            gtvlA += (v2f){cA.w, cA.w} * w12;
            v01B  += (v2f){cB.x, cB.y} * wvv;
            v2atB += (v2f){cB.z, cB.w} * wv0;
            gtvlB += (v2f){cB.w, cB.w} * w12;
        }
        vA0 = v01A.x; vA1 = v01A.y; vA2 = v2atA.x;
        gtA = gtvlA.x; vlA = gtvlA.y;
        vB0 = v01B.x; vB1 = v01B.y; vB2 = v2atB.x;
        gtB = gtvlB.x; vlB = gtvlB.y;
        afeat[(mA*8 + h)*17 + o] = v2atA.y;
        afeat[(mB*8 + h)*17 + o] = v2atB.y;
    }
    __syncthreads();

    // B5: logits (wave 0: 8 slots x 8 heads) + group max/den via shuffles
    if (t < EPB*H_N) {
        int m2 = t >> 3, h2 = t & 7;
        const float* afr = &afeat[(m2*8 + h2)*17];
        float mu = 0.f;
        #pragma unroll 4
        for (int d2 = 0; d2 < DH_N; ++d2) mu += afr[d2];
        mu *= (1.f/DH_N);
        float var = 0.f;
        #pragma unroll 4
        for (int d2 = 0; d2 < DH_N; ++d2) { float dd = afr[d2]-mu; var += dd*dd; }
        var *= (1.f/DH_N);
        float rstd = rsqrtf(var + EPS_F);
        float logit = 0.f;
        #pragma unroll 4
        for (int d2 = 0; d2 < DH_N; ++d2) {
            float xn = (afr[d2]-mu)*rstd*lna_g[d2] + lna_b[d2];
            logit += xn*Wattn[d2];
        }
        int jj = (g<<3) + m2;
        bool vok = jj < u;
        if (vok) {
            int kor = kidx[base + jj];
            attn_raw[h2*(N_Q*K_E) + n*K_E + kor] = logit;
        } else {
            logit = NEGMAX;            // clamped duplicate slot: exact 0 weight
        }
        afeat[(m2*8 + h2)*17 + 16] = logit;
        float mx = logit;
        mx = fmaxf(mx, __shfl_xor(mx, 8));
        mx = fmaxf(mx, __shfl_xor(mx, 16));
        mx = fmaxf(mx, __shfl_xor(mx, 32));
        float ex = expf(logit - mx);
        ex += __shfl_xor(ex, 8);
        ex += __shfl_xor(ex, 16);
        ex += __shfl_xor(ex, 32);
        if (m2 == 0) { mred[h2] = mx; mred[8 + h2] = ex; }
    }
    // gating (register-only, all threads)
    float sactA = vlA / (1.f + expf(-vlA));
    float gA = 1.f / (1.f + expf(-gtA));
    float qA0 = vA0*gA, qA1 = vA1*gA, qA2 = vA2*gA;
    float sactB = vlB / (1.f + expf(-vlB));
    float gB = 1.f / (1.f + expf(-gtB));
    float qB0 = vB0*gB, qB1 = vB1*gB, qB2 = vB2*gB;

    // B6: dtp3
    {
        ch[mA*256 + posA] = make_float4(sactA*evAx, sactA*evAy, sactA*evAz, sactA*esA);
        float dA = qA0*evAx + qA1*evAy + qA2*evAz;
        ch[mA*256 + posB] = make_float4(esA*qA0, esA*qA1, esA*qA2, dA);
        ch[mB*256 + posA] = make_float4(sactB*evBx, sactB*evBy, sactB*evBz, sactB*esB);
        float dB = qB0*evBx + qB1*evBy + qB2*evBz;
        ch[mB*256 + posB] = make_float4(esB*qB0, esB*qB1, esB*qB2, dB);
    }
    __syncthreads();

    // B7: Wval — packed like B2; weight by exp(logit - Mg), stage in w4
    {
        const float bval_r = bval[o];
        v2f u01A = (v2f){0.f, 0.f}, u2sA = (v2f){0.f, bval_r};
        v2f u01B = (v2f){0.f, 0.f}, u2sB = (v2f){0.f, bval_r};
        #pragma unroll 4
        for (int i = 0; i < 32; ++i) {
            int ph = (i + rot2) & 31;
            float4 cA = ch[chA + ph];
            float4 cB = ch[chB + ph];
            float ws = Wval_s[i*16 + o];
            float wv = Wval_v[i*16 + o];
            v2f wvv = (v2f){wv, wv};
            v2f wvs = (v2f){wv, ws};
            u01A += (v2f){cA.x, cA.y} * wvv;
            u2sA += (v2f){cA.z, cA.w} * wvs;
            u01B += (v2f){cB.x, cB.y} * wvv;
            u2sB += (v2f){cB.z, cB.w} * wvs;
        }
        float lA = afeat[(mA*8 + h)*17 + 16];
        float lB = afeat[(mB*8 + h)*17 + 16];
        float Mg = mred[h];
        float wgA = expf(lA - Mg);     // invalid slot: exp(-inf)=0 exact
        float wgB = expf(lB - Mg);
        w4[s*128 + c] = make_float4(wgA*u01A.x + wgB*u01B.x,
                                    wgA*u01A.y + wgB*u01B.y,
                                    wgA*u2sA.x + wgB*u2sB.x,
                                    wgA*u2sA.y + wgB*u2sB.y);
    }
    __syncthreads();

    // tail: combine 4 s-slots -> one partial float4 per channel; emit Mg/deng
    if (t < 128) {
        float4 a = w4[t], b4 = w4[128 + t], c4 = w4[256 + t], d4 = w4[384 + t];
        pbuf[((size_t)(n*4 + g))*D_F + t] =
            make_float4(a.x + b4.x + c4.x + d4.x, a.y + b4.y + c4.y + d4.y,
                        a.z + b4.z + c4.z + d4.z, a.w + b4.w + c4.w + d4.w);
    } else if (t < 144) {
        mbuf[(n*4 + g)*16 + (t - 128)] = mred[t - 128];
    }
}

// ---------------------------------------------------------------------------
// k_finish: TWO n per block (128 threads), packed-FP32 Wo GEMM.
// ---------------------------------------------------------------------------
__global__ __launch_bounds__(128) void k_finish(
    const float4* __restrict__ pbuf, const float* __restrict__ mbuf,
    float* __restrict__ attn_out,     // in: raw logits, out: probabilities
    const float* __restrict__ skip_s, const float* __restrict__ skip_v,
    const float* __restrict__ Wo_s, const float* __restrict__ Wo_v, const float* __restrict__ bo,
    float* __restrict__ out0, float* __restrict__ out1)
{
    const int n0 = blockIdx.x*2, t = threadIdx.x;
    __shared__ float MsDn[32];            // [which][M*8 | Dn*8]
    __shared__ float4 xsh[2*D_F];
    // F1: per-head global max/den for both n (t<64, single wave)
    if (t < 64) {
        int which = t >> 5, tt = t & 31;
        int nn = n0 + which;
        int h3 = tt >> 2, g3 = tt & 3;
        float mg = mbuf[(nn*4 + g3)*16 + h3];
        float dg = mbuf[(nn*4 + g3)*16 + 8 + h3];
        float mx = mg;
        mx = fmaxf(mx, __shfl_xor(mx, 1));
        mx = fmaxf(mx, __shfl_xor(mx, 2));
        float dsc = dg * expf(mg - mx);   // dead group: 0 * 0
        dsc += __shfl_xor(dsc, 1);
        dsc += __shfl_xor(dsc, 2);
        if (g3 == 0) { MsDn[which*16 + h3] = mx; MsDn[which*16 + 8 + h3] = dsc; }
    }
    __syncthreads();
    const int h = t >> 4, o = t & 15;
    // F2: combine group partials for both n; probs in place
    #pragma unroll
    for (int w = 0; w < 2; ++w) {
        int nn = n0 + w;
        const float M = MsDn[w*16 + h];
        const float rden = 1.f / MsDn[w*16 + 8 + h];
        float4 acc = make_float4(0.f, 0.f, 0.f, 0.f);
        #pragma unroll
        for (int gg = 0; gg < 4; ++gg) {
            float mg = mbuf[(nn*4 + gg)*16 + h];
            if (mg > -1e37f) {            // skip dead groups (pbuf unwritten)
                float4 pv = pbuf[((size_t)(nn*4 + gg))*D_F + t];
                float sf = expf(mg - M) * rden;
                acc.x += pv.x*sf; acc.y += pv.y*sf; acc.z += pv.z*sf; acc.w += pv.w*sf;
            }
        }
        xsh[w*D_F + t] = acc;
        #pragma unroll
        for (int kk = 0; kk < 2; ++kk) {
            size_t idx = (size_t)h*(N_Q*K_E) + (size_t)nn*K_E + (o + kk*16);
            attn_out[idx] = expf(attn_out[idx] - M) * rden;
        }
    }
    __syncthreads();
    // F3: Wo GEMM, one weight load -> both n, packed pairs
    float bo_r = bo[t];
    v2f xy0 = (v2f){0.f, 0.f}, zs0 = (v2f){0.f, bo_r};
    v2f xy1 = (v2f){0.f, 0.f}, zs1 = (v2f){0.f, bo_r};
    #pragma unroll 4
    for (int i = 0; i < D_F; ++i) {
        float ws = Wo_s[i*D_F + t];
        float wv = Wo_v[i*D_F + t];
        v2f wvv = (v2f){wv, wv};
        v2f wvs = (v2f){wv, ws};
        float4 x0 = xsh[i];
        float4 x1 = xsh[D_F + i];
        xy0 += (v2f){x0.x, x0.y} * wvv;
        zs0 += (v2f){x0.z, x0.w} * wvs;
        xy1 += (v2f){x1.x, x1.y} * wvv;
        zs1 += (v2f){x1.z, x1.w} * wvs;
    }
    out0[n0*D_F + t] = zs0.y + skip_s[n0*D_F + t];
    out1[(n0*D_F + t)*3 + 0] = xy0.x + skip_v[(n0*D_F + t)*3 + 0];
    out1[(n0*D_F + t)*3 + 1] = xy0.y + skip_v[(n0*D_F + t)*3 + 1];
    out1[(n0*D_F + t)*3 + 2] = zs0.x + skip_v[(n0*D_F + t)*3 + 2];
    const int n1 = n0 + 1;
    out0[n1*D_F + t] = zs1.y + skip_s[n1*D_F + t];
    out1[(n1*D_F + t)*3 + 0] = xy1.x + skip_v[(n1*D_F + t)*3 + 0];
    out1[(n1*D_F + t)*3 + 1] = xy1.y + skip_v[(n1*D_F + t)*3 + 1];
    out1[(n1*D_F + t)*3 + 2] = zs1.x + skip_v[(n1*D_F + t)*3 + 2];
}

// ---------------------------------------------------------------------------
extern "C" void kernel_launch(void* const* d_in, const int* in_sizes, int n_in,
                              void* d_out, int out_size, void* d_ws, size_t ws_size,
                              hipStream_t stream)
{
    (void)in_sizes; (void)n_in; (void)out_size; (void)ws_size;

    const float* query_s = (const float*)d_in[0];
    const float* query_v = (const float*)d_in[1];
    const float* key_s   = (const float*)d_in[2];
    const float* key_v   = (const float*)d_in[3];
    const float* eis     = (const float*)d_in[4];
    const float* eiv     = (const float*)d_in[5];
    const float* eemb    = (const float*)d_in[6];
    const int*   mask    = (const int*)d_in[7];
    const int*   knn     = (const int*)d_in[8];
    const float* Wq_s    = (const float*)d_in[9];
    const float* Wq_v    = (const float*)d_in[10];
    const float* bq      = (const float*)d_in[11];
    const float* Wk_s    = (const float*)d_in[12];
    const float* Wk_v    = (const float*)d_in[13];
    const float* bk      = (const float*)d_in[14];
    const float* Wqk_s   = (const float*)d_in[15];
    const float* Wqk_v   = (const float*)d_in[16];
    const float* bqk     = (const float*)d_in[17];
    const float* Wdtp    = (const float*)d_in[18];
    const float* bdtp    = (const float*)d_in[19];
    const float* Wagv_s  = (const float*)d_in[20];
    const float* bagv    = (const float*)d_in[21];
    const float* Wagv_v  = (const float*)d_in[22];
    const float* Wattn   = (const float*)d_in[23];
    const float* Wval_s  = (const float*)d_in[24];
    const float* Wval_v  = (const float*)d_in[25];
    const float* bval    = (const float*)d_in[26];
    const float* Wo_s    = (const float*)d_in[27];
    const float* Wo_v    = (const float*)d_in[28];
    const float* bo      = (const float*)d_in[29];
    const float* ln_gs   = (const float*)d_in[30];
    const float* ln_bs   = (const float*)d_in[31];
    const float* ln_gv   = (const float*)d_in[32];
    const float* lna_g   = (const float*)d_in[33];
    const float* lna_b   = (const float*)d_in[34];

    float* out      = (float*)d_out;
    float* out_s    = out;
    float* out_v    = out + N_Q*D_F;
    float* out_attn = out + N_Q*D_F*4;

    float* ws = (float*)d_ws;
    float4* q4     = (float4*)ws;                      // N*128 f4 = 4 MB
    float4* k4     = q4 + N_Q*D_F;                     // 4 MB
    float*  skip_s = (float*)(k4 + N_Q*D_F);           // 1 MB
    float*  skip_v = skip_s + N_Q*D_F;                 // 3 MB
    float4* pbuf   = (float4*)(skip_v + N_Q*D_F*3);    // N*4*128 f4 = 16 MB
    float*  mbuf   = (float*)(pbuf + N_Q*4*D_F);       // N*4*16 f = 512 KB
    int*    kidx   = (int*)(mbuf + N_Q*4*16);          // N*K ints = 256 KB
    int*    ucnt   = kidx + N_Q*K_E;                   // N ints

    hipLaunchKernelGGL(k_qk, dim3(2*N_Q), dim3(D_F), 0, stream,
                       query_s, query_v, key_s, key_v,
                       Wq_s, Wq_v, bq, Wk_s, Wk_v, bk,
                       ln_gs, ln_bs, ln_gv, mask,
                       q4, k4, skip_s, skip_v,
                       kidx, ucnt, out_attn, mbuf);
    hipLaunchKernelGGL(k_edge_flash, dim3(N_Q*K_E/EPB), dim3(512), 0, stream,
                       q4, k4, eis, eiv, eemb, knn, kidx, ucnt,
                       Wqk_s, Wqk_v, bqk, Wdtp, bdtp,
                       Wagv_s, bagv, Wagv_v, Wattn, lna_g, lna_b,
                       Wval_s, Wval_v, bval,
                       pbuf, mbuf, out_attn);
    hipLaunchKernelGGL(k_finish, dim3(N_Q/2), dim3(D_F), 0, stream,
                       pbuf, mbuf, out_attn, skip_s, skip_v, Wo_s, Wo_v, bo,
                       out_s, out_v);
}

// Round 15
// 412.729 us; speedup vs baseline: 1.3408x; 1.0131x over previous
//
#include <hip/hip_runtime.h>
#include <hip/hip_bf16.h>
#include <math.h>

#define N_Q 2048
#define K_E 32
#define D_F 128
#define H_N 8
#define DH_N 16
#define EPS_F 1e-5f
#define NEGMAX -3.4028235e38f
#define EPB 8      // edges per edge-block

typedef __attribute__((ext_vector_type(2))) float v2f;

// R26: R25 (418us best; edge untouched here) + non-edge batching:
//  (1) k_qk: 2 n per block (query pairs, key pairs) -- each Wq/Wk weight
//      load feeds both n's packed FMAs; weight traffic + issue ~halved.
//      Mask prep: wave0 -> n0, wave1 -> n1 (same ballot code, tt = t&63).
//  (2) k_finish: 4 n per block (Wo stream amortized 4x, static unroll).
// Edge kernel byte-identical to R25. Same per-n arithmetic order -> same
// absmax. Pre-commit: if non-edge shrinks <15us, residual is launch fixed
// cost -> plateau.

// ---------------------------------------------------------------------------
// k_qk: blocks [0, N/2): query pair (LN + Wq + mask prep for n0,n1).
//       blocks [N/2, N): key pair (Wk for n0,n1).
// Outputs packed float4: .xyz = vector part, .w = scalar part.
// ---------------------------------------------------------------------------
__global__ __launch_bounds__(128) void k_qk(
    const float* __restrict__ qs_in, const float* __restrict__ qv_in,
    const float* __restrict__ ks_in, const float* __restrict__ kv_in,
    const float* __restrict__ Wq_s, const float* __restrict__ Wq_v, const float* __restrict__ bq,
    const float* __restrict__ Wk_s, const float* __restrict__ Wk_v, const float* __restrict__ bk,
    const float* __restrict__ ln_gs, const float* __restrict__ ln_bs, const float* __restrict__ ln_gv,
    const int* __restrict__ mask,
    float4* __restrict__ q4, float4* __restrict__ k4,
    float* __restrict__ skip_s, float* __restrict__ skip_v,
    int* __restrict__ kidx, int* __restrict__ ucnt,
    float* __restrict__ attn_raw, float* __restrict__ mbuf)
{
    const int t = threadIdx.x;
    __shared__ __align__(16) float raw0[D_F*3], raw1[D_F*3];
    __shared__ float4 sv0[D_F], sv1[D_F];
    __shared__ float red[12];
    if (blockIdx.x < N_Q/2) {
        const int n0 = blockIdx.x*2, n1 = n0 + 1;
        // ---- fused k_prep: wave0 -> n0, wave1 -> n1 ----
        {
            int which = t >> 6;
            int nn = n0 + which;
            int tt = t & 63;
            const int k = tt & 31;
            int mk = (tt < 32) ? mask[nn*K_E + k] : 0;
            unsigned long long bal = __ballot(mk != 0);
            int u = (int)__popcll(bal);
            if (tt < 32 && mk) {
                int pos = (int)__popcll(bal & ((1ull << k) - 1ull));
                kidx[nn*K_E + pos] = k;
            }
            if (tt == 0) ucnt[nn] = u;
            if (mask[nn*K_E + k] == 0) {
                int hb = (tt >> 5) * 4;
                #pragma unroll
                for (int hh = 0; hh < 4; ++hh)
                    attn_raw[(size_t)(hb + hh)*(N_Q*K_E) + nn*K_E + k] = NEGMAX;
            }
            int gU = (u + 7) >> 3;
            if (tt < 16) {
                for (int g2 = gU; g2 < 4; ++g2)
                    mbuf[(nn*4 + g2)*16 + tt] = (tt < 8) ? NEGMAX : 0.f;
            }
        }
        // ---- LN for both n ----
        float sval0 = qs_in[n0*D_F + t];
        float sval1 = qs_in[n1*D_F + t];
        float ssqp0 = 0.f, ssqp1 = 0.f;
        if (t < 96) {
            float4 rv0 = ((const float4*)(qv_in + (size_t)n0*D_F*3))[t];
            float4 rv1 = ((const float4*)(qv_in + (size_t)n1*D_F*3))[t];
            ((float4*)raw0)[t] = rv0;
            ((float4*)raw1)[t] = rv1;
            ssqp0 = rv0.x*rv0.x + rv0.y*rv0.y + rv0.z*rv0.z + rv0.w*rv0.w;
            ssqp1 = rv1.x*rv1.x + rv1.y*rv1.y + rv1.z*rv1.z + rv1.w*rv1.w;
        }
        float r0 = sval0, r1 = sval0*sval0, r2 = ssqp0;
        float r3 = sval1, r4 = sval1*sval1, r5 = ssqp1;
        #pragma unroll
        for (int m = 1; m < 64; m <<= 1) {
            r0 += __shfl_xor(r0, m);
            r1 += __shfl_xor(r1, m);
            r2 += __shfl_xor(r2, m);
            r3 += __shfl_xor(r3, m);
            r4 += __shfl_xor(r4, m);
            r5 += __shfl_xor(r5, m);
        }
        if ((t & 63) == 0) {
            int w = t >> 6;
            red[w*6+0] = r0; red[w*6+1] = r1; red[w*6+2] = r2;
            red[w*6+3] = r3; red[w*6+4] = r4; red[w*6+5] = r5;
        }
        __syncthreads();
        float tS0 = red[0]+red[6],  tS20 = red[1]+red[7],  tQ0 = red[2]+red[8];
        float tS1 = red[3]+red[9],  tS21 = red[4]+red[10], tQ1 = red[5]+red[11];
        float gs = ln_gs[t], bs = ln_bs[t], gv = ln_gv[t];
        float mu0 = tS0 * (1.f/D_F);
        float var0 = fmaxf(tS20*(1.f/D_F) - mu0*mu0, 0.f);
        float rstd0 = rsqrtf(var0 + EPS_F);
        float rrms0 = rsqrtf(tQ0*(1.f/D_F) + EPS_F);
        float a0s = (sval0 - mu0)*rstd0*gs + bs;
        skip_s[n0*D_F + t] = a0s;
        float b00 = raw0[t*3+0]*rrms0*gv;
        float b01 = raw0[t*3+1]*rrms0*gv;
        float b02 = raw0[t*3+2]*rrms0*gv;
        skip_v[(n0*D_F + t)*3 + 0] = b00;
        skip_v[(n0*D_F + t)*3 + 1] = b01;
        skip_v[(n0*D_F + t)*3 + 2] = b02;
        sv0[t] = make_float4(b00, b01, b02, a0s);
        float mu1 = tS1 * (1.f/D_F);
        float var1 = fmaxf(tS21*(1.f/D_F) - mu1*mu1, 0.f);
        float rstd1 = rsqrtf(var1 + EPS_F);
        float rrms1 = rsqrtf(tQ1*(1.f/D_F) + EPS_F);
        float a1s = (sval1 - mu1)*rstd1*gs + bs;
        skip_s[n1*D_F + t] = a1s;
        float b10 = raw1[t*3+0]*rrms1*gv;
        float b11 = raw1[t*3+1]*rrms1*gv;
        float b12 = raw1[t*3+2]*rrms1*gv;
        skip_v[(n1*D_F + t)*3 + 0] = b10;
        skip_v[(n1*D_F + t)*3 + 1] = b11;
        skip_v[(n1*D_F + t)*3 + 2] = b12;
        sv1[t] = make_float4(b10, b11, b12, a1s);
        __syncthreads();
        float bq_r = bq[t];
        v2f a01_0 = (v2f){0.f, 0.f}, a2s_0 = (v2f){0.f, bq_r};
        v2f a01_1 = (v2f){0.f, 0.f}, a2s_1 = (v2f){0.f, bq_r};
        #pragma unroll 4
        for (int i = 0; i < D_F; ++i) {
            float4 p0 = sv0[i];
            float4 p1 = sv1[i];
            float ws = Wq_s[i*D_F + t];
            float wv = Wq_v[i*D_F + t];
            v2f wvv = (v2f){wv, wv};
            v2f wvs = (v2f){wv, ws};
            a01_0 += (v2f){p0.x, p0.y} * wvv;
            a2s_0 += (v2f){p0.z, p0.w} * wvs;
            a01_1 += (v2f){p1.x, p1.y} * wvv;
            a2s_1 += (v2f){p1.z, p1.w} * wvs;
        }
        q4[n0*D_F + t] = make_float4(a01_0.x, a01_0.y, a2s_0.x, a2s_0.y);
        q4[n1*D_F + t] = make_float4(a01_1.x, a01_1.y, a2s_1.x, a2s_1.y);
    } else {
        const int nb = blockIdx.x - N_Q/2;
        const int n0 = nb*2, n1 = n0 + 1;
        float sval0 = ks_in[n0*D_F + t];
        float sval1 = ks_in[n1*D_F + t];
        if (t < 96) {
            ((float4*)raw0)[t] = ((const float4*)(kv_in + (size_t)n0*D_F*3))[t];
            ((float4*)raw1)[t] = ((const float4*)(kv_in + (size_t)n1*D_F*3))[t];
        }
        __syncthreads();
        sv0[t] = make_float4(raw0[t*3+0], raw0[t*3+1], raw0[t*3+2], sval0);
        sv1[t] = make_float4(raw1[t*3+0], raw1[t*3+1], raw1[t*3+2], sval1);
        __syncthreads();
        float bk_r = bk[t];
        v2f a01_0 = (v2f){0.f, 0.f}, a2s_0 = (v2f){0.f, bk_r};
        v2f a01_1 = (v2f){0.f, 0.f}, a2s_1 = (v2f){0.f, bk_r};
        #pragma unroll 4
        for (int i = 0; i < D_F; ++i) {
            float4 p0 = sv0[i];
            float4 p1 = sv1[i];
            float ws = Wk_s[i*D_F + t];
            float wv = Wk_v[i*D_F + t];
            v2f wvv = (v2f){wv, wv};
            v2f wvs = (v2f){wv, ws};
            a01_0 += (v2f){p0.x, p0.y} * wvv;
            a2s_0 += (v2f){p0.z, p0.w} * wvs;
            a01_1 += (v2f){p1.x, p1.y} * wvv;
            a2s_1 += (v2f){p1.z, p1.w} * wvs;
        }
        k4[n0*D_F + t] = make_float4(a01_0.x, a01_0.y, a2s_0.x, a2s_0.y);
        k4[n1*D_F + t] = make_float4(a01_1.x, a01_1.y, a2s_1.x, a2s_1.y);
    }
}

// ---------------------------------------------------------------------------
// k_edge_flash: byte-identical to R25 (compacted slots, g-major mapping,
// packed-FP32 accumulation in stage A / B2 / B4 / B7).
// ---------------------------------------------------------------------------
__global__ __launch_bounds__(512, 6) void k_edge_flash(
    const float4* __restrict__ q4, const float4* __restrict__ k4,
    const float* __restrict__ eis, const float* __restrict__ eiv,
    const float* __restrict__ eemb,
    const int* __restrict__ knn,
    const int* __restrict__ kidx, const int* __restrict__ ucnt,
    const float* __restrict__ Wqk_s, const float* __restrict__ Wqk_v, const float* __restrict__ bqk,
    const float* __restrict__ Wdtp, const float* __restrict__ bdtp,
    const float* __restrict__ Wagv_s, const float* __restrict__ bagv, const float* __restrict__ Wagv_v,
    const float* __restrict__ Wattn, const float* __restrict__ lna_g, const float* __restrict__ lna_b,
    const float* __restrict__ Wval_s, const float* __restrict__ Wval_v, const float* __restrict__ bval,
    float4* __restrict__ pbuf, float* __restrict__ mbuf, float* __restrict__ attn_raw)
{
    const int n = blockIdx.x & (N_Q - 1);   // g-major: XCD = n%8 per plane
    const int g = blockIdx.x >> 11;
    const int base = n*K_E;
    const int u = ucnt[n];
    if ((g << 3) >= u) return;         // dead group: mbuf prefilled in k_qk

    const int t = threadIdx.x;
    const int s = t >> 7, c = t & 127, h = (t >> 4) & 7, o = t & 15;
    const int rot2 = h * 2;

    __shared__ float4 ch[EPB*256];     // 32 KB (stage-A ee aliased here)
    __shared__ float4 w4[EPB*128];     // 16 KB; reused as partial-combine stage
    __shared__ float  afeat[EPB*8*17]; // 4.25 KB: 16 feats + logit col 16
    __shared__ float  mred[16];        // Mg[8], deng[8]

    // stage A: ee gather (compacted, transposed, aliased into ch) + w GEMM
    {
        float* ee = (float*)ch;        // [128][8] floats = 4 KB
        {
            int idx = t; int m = idx & 7, i = idx >> 3;
            int jj = (g<<3) + m; jj = (jj < u) ? jj : (u-1);
            int e = base + kidx[base + jj];
            ee[i*EPB+m] = eemb[(size_t)e*D_F + i];
        }
        {
            int idx = t + 512; int m = idx & 7, i = idx >> 3;
            int jj = (g<<3) + m; jj = (jj < u) ? jj : (u-1);
            int e = base + kidx[base + jj];
            ee[i*EPB+m] = eemb[(size_t)e*D_F + i];
        }
        __syncthreads();
        float b = bdtp[t];
        v2f acc2[4];
        #pragma unroll
        for (int j = 0; j < 4; ++j) acc2[j] = (v2f){b, b};
        const float4* ee4 = (const float4*)ch;
        #pragma unroll 2
        for (int i = 0; i < D_F; ++i) {
            float wv = Wdtp[i*512 + t];
            v2f wv2 = (v2f){wv, wv};
            float4 e0 = ee4[i*2];      // ds_read_b128, broadcast conflict-free
            float4 e1 = ee4[i*2+1];
            acc2[0] += (v2f){e0.x, e0.y} * wv2;
            acc2[1] += (v2f){e0.z, e0.w} * wv2;
            acc2[2] += (v2f){e1.x, e1.y} * wv2;
            acc2[3] += (v2f){e1.z, e1.w} * wv2;
        }
        __syncthreads();               // all ee reads done -> ch reusable
        float* w4f = (float*)w4;
        const int chn = t & 127, sel = t >> 7;
        #pragma unroll
        for (int m = 0; m < EPB; ++m)
            w4f[(m*128 + chn)*4 + sel] = acc2[m >> 1][m & 1];
    }

    const int mA = s, mB = s + 4;
    int jA = (g<<3) + mA; jA = (jA < u) ? jA : (u-1);
    int jB = (g<<3) + mB; jB = (jB < u) ? jB : (u-1);
    const int eA = base + kidx[base + jA];
    const int eB = base + kidx[base + jB];

    const float esA = eis[eA], esB = eis[eB];
    const float evAx = eiv[eA*3+0], evAy = eiv[eA*3+1], evAz = eiv[eA*3+2];
    const float evBx = eiv[eB*3+0], evBy = eiv[eB*3+1], evBz = eiv[eB*3+2];

    // B1: dtp1 straight from global
    {
        float4 q  = q4[(size_t)n*D_F + c];
        float4 kA = k4[(size_t)knn[eA]*D_F + c];
        float4 kB = k4[(size_t)knn[eB]*D_F + c];
        const int hp = c >> 5, jc = c & 31;
        const int pos0 = hp*32 + ((jc + 2*hp) & 31);
        const int pos1 = (hp+4)*32 + ((jc + 2*(hp+4)) & 31);
        ch[mA*256 + pos0] = make_float4(q.w*kA.x, q.w*kA.y, q.w*kA.z, q.w*kA.w);
        ch[mA*256 + pos1] = make_float4(kA.w*q.x, kA.w*q.y, kA.w*q.z,
                                        q.x*kA.x + q.y*kA.y + q.z*kA.z);
        ch[mB*256 + pos0] = make_float4(q.w*kB.x, q.w*kB.y, q.w*kB.z, q.w*kB.w);
        ch[mB*256 + pos1] = make_float4(kB.w*q.x, kB.w*q.y, kB.w*q.z,
                                        q.x*kB.x + q.y*kB.y + q.z*kB.z);
    }
    __syncthreads();

    const int chA = mA*256 + h*32, chB = mB*256 + h*32;

    // B2: Wqk — packed
    float pAs, pA0, pA1, pA2, pBs, pB0, pB1, pB2;
    {
        const float bqk_r = bqk[o];
        v2f a01A = (v2f){0.f, 0.f}, a2sA = (v2f){0.f, bqk_r};
        v2f a01B = (v2f){0.f, 0.f}, a2sB = (v2f){0.f, bqk_r};
        #pragma unroll 4
        for (int i = 0; i < 32; ++i) {
            int ph = (i + rot2) & 31;
            float4 cA = ch[chA + ph];
            float4 cB = ch[chB + ph];
            float ws = Wqk_s[i*16 + o];
            float wv = Wqk_v[i*16 + o];
            v2f wvv = (v2f){wv, wv};
            v2f wvs = (v2f){wv, ws};
            a01A += (v2f){cA.x, cA.y} * wvv;
            a2sA += (v2f){cA.z, cA.w} * wvs;
            a01B += (v2f){cB.x, cB.y} * wvv;
            a2sB += (v2f){cB.z, cB.w} * wvs;
        }
        pA0 = a01A.x; pA1 = a01A.y; pA2 = a2sA.x; pAs = a2sA.y;
        pB0 = a01B.x; pB1 = a01B.y; pB2 = a2sB.x; pBs = a2sB.y;
    }
    __syncthreads();

    const int posA = h*32 + ((o + rot2) & 31);
    const int posB = h*32 + ((o + 16 + rot2) & 31);

    // B3: dtp2 (weighted)
    {
        float4 wA = w4[mA*128 + c];
        float4 wB = w4[mB*128 + c];
        ch[mA*256 + posA] = make_float4(pAs*evAx*wA.z, pAs*evAy*wA.z, pAs*evAz*wA.z, pAs*esA*wA.x);
        float dA = pA0*evAx + pA1*evAy + pA2*evAz;
        ch[mA*256 + posB] = make_float4(esA*pA0*wA.w, esA*pA1*wA.w, esA*pA2*wA.w, dA*wA.y);
        ch[mB*256 + posA] = make_float4(pBs*evBx*wB.z, pBs*evBy*wB.z, pBs*evBz*wB.z, pBs*esB*wB.x);
        float dB = pB0*evBx + pB1*evBy + pB2*evBz;
        ch[mB*256 + posB] = make_float4(esB*pB0*wB.w, esB*pB1*wB.w, esB*pB2*wB.w, dB*wB.y);
    }
    __syncthreads();

    // B4: Wagv — packed
    float gtA, vlA, vA0, vA1, vA2, gtB, vlB, vB0, vB1, vB2;
    {
        const float bag0 = bagv[h*48 + o];
        const float bag1 = bagv[h*48 + 16 + o];
        const float bag2 = bagv[h*48 + 32 + o];
        v2f v01A = (v2f){0.f, 0.f}, v2atA = (v2f){0.f, bag0}, gtvlA = (v2f){bag1, bag2};
        v2f v01B = (v2f){0.f, 0.f}, v2atB = (v2f){0.f, bag0}, gtvlB = (v2f){bag1, bag2};
        #pragma unroll 4
        for (int i = 0; i < 32; ++i) {
            int ph = (i + rot2) & 31;
            float4 cA = ch[chA + ph];
            float4 cB = ch[chB + ph];
            const float* wrow = &Wagv_s[(h*32+i)*48];
            float w0 = wrow[o], w1 = wrow[16+o], w2 = wrow[32+o];
            float wv = Wagv_v[(h*32+i)*16 + o];
            v2f wvv = (v2f){wv, wv};
            v2f wv0 = (v2f){wv, w0};
            v2f w12 = (v2f){w1, w2};
            v01A  += (v2f){cA.x, cA.y} * wvv;
            v2atA += (v2f){cA.z, cA.w} * wv0;
            gtvlA += (v2f){cA.w, cA.w} * w12;
            v01B  += (v2f){cB.x, cB.y} * wvv;
            v2atB += (v2f){cB.z, cB.w} * wv0;
            gtvlB += (v2f){cB.w, cB.w} * w12;
        }
        vA0 = v01A.x; vA1 = v01A.y; vA2 = v2atA.x;
        gtA = gtvlA.x; vlA = gtvlA.y;
        vB0 = v01B.x; vB1 = v01B.y; vB2 = v2atB.x;
        gtB = gtvlB.x; vlB = gtvlB.y;
        afeat[(mA*8 + h)*17 + o] = v2atA.y;
        afeat[(mB*8 + h)*17 + o] = v2atB.y;
    }
    __syncthreads();

    // B5: logits (wave 0: 8 slots x 8 heads) + group max/den via shuffles
    if (t < EPB*H_N) {
        int m2 = t >> 3, h2 = t & 7;
        const float* afr = &afeat[(m2*8 + h2)*17];
        float mu = 0.f;
        #pragma unroll 4
        for (int d2 = 0; d2 < DH_N; ++d2) mu += afr[d2];
        mu *= (1.f/DH_N);
        float var = 0.f;
        #pragma unroll 4
        for (int d2 = 0; d2 < DH_N; ++d2) { float dd = afr[d2]-mu; var += dd*dd; }
        var *= (1.f/DH_N);
        float rstd = rsqrtf(var + EPS_F);
        float logit = 0.f;
        #pragma unroll 4
        for (int d2 = 0; d2 < DH_N; ++d2) {
            float xn = (afr[d2]-mu)*rstd*lna_g[d2] + lna_b[d2];
            logit += xn*Wattn[d2];
        }
        int jj = (g<<3) + m2;
        bool vok = jj < u;
        if (vok) {
            int kor = kidx[base + jj];
            attn_raw[h2*(N_Q*K_E) + n*K_E + kor] = logit;
        } else {
            logit = NEGMAX;            // clamped duplicate slot: exact 0 weight
        }
        afeat[(m2*8 + h2)*17 + 16] = logit;
        float mx = logit;
        mx = fmaxf(mx, __shfl_xor(mx, 8));
        mx = fmaxf(mx, __shfl_xor(mx, 16));
        mx = fmaxf(mx, __shfl_xor(mx, 32));
        float ex = expf(logit - mx);
        ex += __shfl_xor(ex, 8);
        ex += __shfl_xor(ex, 16);
        ex += __shfl_xor(ex, 32);
        if (m2 == 0) { mred[h2] = mx; mred[8 + h2] = ex; }
    }
    // gating (register-only, all threads)
    float sactA = vlA / (1.f + expf(-vlA));
    float gA = 1.f / (1.f + expf(-gtA));
    float qA0 = vA0*gA, qA1 = vA1*gA, qA2 = vA2*gA;
    float sactB = vlB / (1.f + expf(-vlB));
    float gB = 1.f / (1.f + expf(-gtB));
    float qB0 = vB0*gB, qB1 = vB1*gB, qB2 = vB2*gB;

    // B6: dtp3
    {
        ch[mA*256 + posA] = make_float4(sactA*evAx, sactA*evAy, sactA*evAz, sactA*esA);
        float dA = qA0*evAx + qA1*evAy + qA2*evAz;
        ch[mA*256 + posB] = make_float4(esA*qA0, esA*qA1, esA*qA2, dA);
        ch[mB*256 + posA] = make_float4(sactB*evBx, sactB*evBy, sactB*evBz, sactB*esB);
        float dB = qB0*evBx + qB1*evBy + qB2*evBz;
        ch[mB*256 + posB] = make_float4(esB*qB0, esB*qB1, esB*qB2, dB);
    }
    __syncthreads();

    // B7: Wval — packed; weight by exp(logit - Mg), stage in w4
    {
        const float bval_r = bval[o];
        v2f u01A = (v2f){0.f, 0.f}, u2sA = (v2f){0.f, bval_r};
        v2f u01B = (v2f){0.f, 0.f}, u2sB = (v2f){0.f, bval_r};
        #pragma unroll 4
        for (int i = 0; i < 32; ++i) {
            int ph = (i + rot2) & 31;
            float4 cA = ch[chA + ph];
            float4 cB = ch[chB + ph];
            float ws = Wval_s[i*16 + o];
            float wv = Wval_v[i*16 + o];
            v2f wvv = (v2f){wv, wv};
            v2f wvs = (v2f){wv, ws};
            u01A += (v2f){cA.x, cA.y} * wvv;
            u2sA += (v2f){cA.z, cA.w} * wvs;
            u01B += (v2f){cB.x, cB.y} * wvv;
            u2sB += (v2f){cB.z, cB.w} * wvs;
        }
        float lA = afeat[(mA*8 + h)*17 + 16];
        float lB = afeat[(mB*8 + h)*17 + 16];
        float Mg = mred[h];
        float wgA = expf(lA - Mg);     // invalid slot: exp(-inf)=0 exact
        float wgB = expf(lB - Mg);
        w4[s*128 + c] = make_float4(wgA*u01A.x + wgB*u01B.x,
                                    wgA*u01A.y + wgB*u01B.y,
                                    wgA*u2sA.x + wgB*u2sB.x,
                                    wgA*u2sA.y + wgB*u2sB.y);
    }
    __syncthreads();

    // tail: combine 4 s-slots -> one partial float4 per channel; emit Mg/deng
    if (t < 128) {
        float4 a = w4[t], b4 = w4[128 + t], c4 = w4[256 + t], d4 = w4[384 + t];
        pbuf[((size_t)(n*4 + g))*D_F + t] =
            make_float4(a.x + b4.x + c4.x + d4.x, a.y + b4.y + c4.y + d4.y,
                        a.z + b4.z + c4.z + d4.z, a.w + b4.w + c4.w + d4.w);
    } else if (t < 144) {
        mbuf[(n*4 + g)*16 + (t - 128)] = mred[t - 128];
    }
}

// ---------------------------------------------------------------------------
// k_finish: FOUR n per block (128 threads), packed-FP32 Wo GEMM; each Wo
// weight load feeds all 4 n.
// ---------------------------------------------------------------------------
__global__ __launch_bounds__(128) void k_finish(
    const float4* __restrict__ pbuf, const float* __restrict__ mbuf,
    float* __restrict__ attn_out,     // in: raw logits, out: probabilities
    const float* __restrict__ skip_s, const float* __restrict__ skip_v,
    const float* __restrict__ Wo_s, const float* __restrict__ Wo_v, const float* __restrict__ bo,
    float* __restrict__ out0, float* __restrict__ out1)
{
    const int n0 = blockIdx.x*4, t = threadIdx.x;
    __shared__ float MsDn[64];            // [which*16 + (M 0-7 | Dn 8-15)]
    __shared__ float4 xsh[4*D_F];         // 8 KB
    // F1: per-head global max/den for 4 n (all 128 threads)
    {
        int which = t >> 5, tt = t & 31;
        int nn = n0 + which;
        int h3 = tt >> 2, g3 = tt & 3;
        float mg = mbuf[(nn*4 + g3)*16 + h3];
        float dg = mbuf[(nn*4 + g3)*16 + 8 + h3];
        float mx = mg;
        mx = fmaxf(mx, __shfl_xor(mx, 1));
        mx = fmaxf(mx, __shfl_xor(mx, 2));
        float dsc = dg * expf(mg - mx);   // dead group: 0 * 0
        dsc += __shfl_xor(dsc, 1);
        dsc += __shfl_xor(dsc, 2);
        if (g3 == 0) { MsDn[which*16 + h3] = mx; MsDn[which*16 + 8 + h3] = dsc; }
    }
    __syncthreads();
    const int h = t >> 4, o = t & 15;
    // F2: combine group partials for all 4 n; probs in place
    #pragma unroll
    for (int w = 0; w < 4; ++w) {
        int nn = n0 + w;
        const float M = MsDn[w*16 + h];
        const float rden = 1.f / MsDn[w*16 + 8 + h];
        float4 acc = make_float4(0.f, 0.f, 0.f, 0.f);
        #pragma unroll
        for (int gg = 0; gg < 4; ++gg) {
            float mg = mbuf[(nn*4 + gg)*16 + h];
            if (mg > -1e37f) {            // skip dead groups (pbuf unwritten)
                float4 pv = pbuf[((size_t)(nn*4 + gg))*D_F + t];
                float sf = expf(mg - M) * rden;
                acc.x += pv.x*sf; acc.y += pv.y*sf; acc.z += pv.z*sf; acc.w += pv.w*sf;
            }
        }
        xsh[w*D_F + t] = acc;
        #pragma unroll
        for (int kk = 0; kk < 2; ++kk) {
            size_t idx = (size_t)h*(N_Q*K_E) + (size_t)nn*K_E + (o + kk*16);
            attn_out[idx] = expf(attn_out[idx] - M) * rden;
        }
    }
    __syncthreads();
    // F3: Wo GEMM, one weight load -> 4 n, packed pairs (static unroll)
    float bo_r = bo[t];
    v2f xy0 = (v2f){0.f, 0.f}, zs0 = (v2f){0.f, bo_r};
    v2f xy1 = (v2f){0.f, 0.f}, zs1 = (v2f){0.f, bo_r};
    v2f xy2 = (v2f){0.f, 0.f}, zs2 = (v2f){0.f, bo_r};
    v2f xy3 = (v2f){0.f, 0.f}, zs3 = (v2f){0.f, bo_r};
    #pragma unroll 4
    for (int i = 0; i < D_F; ++i) {
        float ws = Wo_s[i*D_F + t];
        float wv = Wo_v[i*D_F + t];
        v2f wvv = (v2f){wv, wv};
        v2f wvs = (v2f){wv, ws};
        float4 x0 = xsh[i];
        float4 x1 = xsh[D_F + i];
        float4 x2 = xsh[2*D_F + i];
        float4 x3 = xsh[3*D_F + i];
        xy0 += (v2f){x0.x, x0.y} * wvv;  zs0 += (v2f){x0.z, x0.w} * wvs;
        xy1 += (v2f){x1.x, x1.y} * wvv;  zs1 += (v2f){x1.z, x1.w} * wvs;
        xy2 += (v2f){x2.x, x2.y} * wvv;  zs2 += (v2f){x2.z, x2.w} * wvs;
        xy3 += (v2f){x3.x, x3.y} * wvv;  zs3 += (v2f){x3.z, x3.w} * wvs;
    }
    {
        int nn = n0;
        out0[nn*D_F + t] = zs0.y + skip_s[nn*D_F + t];
        out1[(nn*D_F + t)*3 + 0] = xy0.x + skip_v[(nn*D_F + t)*3 + 0];
        out1[(nn*D_F + t)*3 + 1] = xy0.y + skip_v[(nn*D_F + t)*3 + 1];
        out1[(nn*D_F + t)*3 + 2] = zs0.x + skip_v[(nn*D_F + t)*3 + 2];
    }
    {
        int nn = n0 + 1;
        out0[nn*D_F + t] = zs1.y + skip_s[nn*D_F + t];
        out1[(nn*D_F + t)*3 + 0] = xy1.x + skip_v[(nn*D_F + t)*3 + 0];
        out1[(nn*D_F + t)*3 + 1] = xy1.y + skip_v[(nn*D_F + t)*3 + 1];
        out1[(nn*D_F + t)*3 + 2] = zs1.x + skip_v[(nn*D_F + t)*3 + 2];
    }
    {
        int nn = n0 + 2;
        out0[nn*D_F + t] = zs2.y + skip_s[nn*D_F + t];
        out1[(nn*D_F + t)*3 + 0] = xy2.x + skip_v[(nn*D_F + t)*3 + 0];
        out1[(nn*D_F + t)*3 + 1] = xy2.y + skip_v[(nn*D_F + t)*3 + 1];
        out1[(nn*D_F + t)*3 + 2] = zs2.x + skip_v[(nn*D_F + t)*3 + 2];
    }
    {
        int nn = n0 + 3;
        out0[nn*D_F + t] = zs3.y + skip_s[nn*D_F + t];
        out1[(nn*D_F + t)*3 + 0] = xy3.x + skip_v[(nn*D_F + t)*3 + 0];
        out1[(nn*D_F + t)*3 + 1] = xy3.y + skip_v[(nn*D_F + t)*3 + 1];
        out1[(nn*D_F + t)*3 + 2] = zs3.x + skip_v[(nn*D_F + t)*3 + 2];
    }
}

// ---------------------------------------------------------------------------
extern "C" void kernel_launch(void* const* d_in, const int* in_sizes, int n_in,
                              void* d_out, int out_size, void* d_ws, size_t ws_size,
                              hipStream_t stream)
{
    (void)in_sizes; (void)n_in; (void)out_size; (void)ws_size;

    const float* query_s = (const float*)d_in[0];
    const float* query_v = (const float*)d_in[1];
    const float* key_s   = (const float*)d_in[2];
    const float* key_v   = (const float*)d_in[3];
    const float* eis     = (const float*)d_in[4];
    const float* eiv     = (const float*)d_in[5];
    const float* eemb    = (const float*)d_in[6];
    const int*   mask    = (const int*)d_in[7];
    const int*   knn     = (const int*)d_in[8];
    const float* Wq_s    = (const float*)d_in[9];
    const float* Wq_v    = (const float*)d_in[10];
    const float* bq      = (const float*)d_in[11];
    const float* Wk_s    = (const float*)d_in[12];
    const float* Wk_v    = (const float*)d_in[13];
    const float* bk      = (const float*)d_in[14];
    const float* Wqk_s   = (const float*)d_in[15];
    const float* Wqk_v   = (const float*)d_in[16];
    const float* bqk     = (const float*)d_in[17];
    const float* Wdtp    = (const float*)d_in[18];
    const float* bdtp    = (const float*)d_in[19];
    const float* Wagv_s  = (const float*)d_in[20];
    const float* bagv    = (const float*)d_in[21];
    const float* Wagv_v  = (const float*)d_in[22];
    const float* Wattn   = (const float*)d_in[23];
    const float* Wval_s  = (const float*)d_in[24];
    const float* Wval_v  = (const float*)d_in[25];
    const float* bval    = (const float*)d_in[26];
    const float* Wo_s    = (const float*)d_in[27];
    const float* Wo_v    = (const float*)d_in[28];
    const float* bo      = (const float*)d_in[29];
    const float* ln_gs   = (const float*)d_in[30];
    const float* ln_bs   = (const float*)d_in[31];
    const float* ln_gv   = (const float*)d_in[32];
    const float* lna_g   = (const float*)d_in[33];
    const float* lna_b   = (const float*)d_in[34];

    float* out      = (float*)d_out;
    float* out_s    = out;
    float* out_v    = out + N_Q*D_F;
    float* out_attn = out + N_Q*D_F*4;

    float* ws = (float*)d_ws;
    float4* q4     = (float4*)ws;                      // N*128 f4 = 4 MB
    float4* k4     = q4 + N_Q*D_F;                     // 4 MB
    float*  skip_s = (float*)(k4 + N_Q*D_F);           // 1 MB
    float*  skip_v = skip_s + N_Q*D_F;                 // 3 MB
    float4* pbuf   = (float4*)(skip_v + N_Q*D_F*3);    // N*4*128 f4 = 16 MB
    float*  mbuf   = (float*)(pbuf + N_Q*4*D_F);       // N*4*16 f = 512 KB
    int*    kidx   = (int*)(mbuf + N_Q*4*16);          // N*K ints = 256 KB
    int*    ucnt   = kidx + N_Q*K_E;                   // N ints

    hipLaunchKernelGGL(k_qk, dim3(N_Q), dim3(D_F), 0, stream,
                       query_s, query_v, key_s, key_v,
                       Wq_s, Wq_v, bq, Wk_s, Wk_v, bk,
                       ln_gs, ln_bs, ln_gv, mask,
                       q4, k4, skip_s, skip_v,
                       kidx, ucnt, out_attn, mbuf);
    hipLaunchKernelGGL(k_edge_flash, dim3(N_Q*K_E/EPB), dim3(512), 0, stream,
                       q4, k4, eis, eiv, eemb, knn, kidx, ucnt,
                       Wqk_s, Wqk_v, bqk, Wdtp, bdtp,
                       Wagv_s, bagv, Wagv_v, Wattn, lna_g, lna_b,
                       Wval_s, Wval_v, bval,
                       pbuf, mbuf, out_attn);
    hipLaunchKernelGGL(k_finish, dim3(N_Q/4), dim3(D_F), 0, stream,
                       pbuf, mbuf, out_attn, skip_s, skip_v, Wo_s, Wo_v, bo,
                       out_s, out_v);
}

// Round 16
// 409.077 us; speedup vs baseline: 1.3527x; 1.0089x over previous
//
#include <hip/hip_runtime.h>
#include <hip/hip_bf16.h>
#include <math.h>

#define N_Q 2048
#define K_E 32
#define D_F 128
#define H_N 8
#define DH_N 16
#define EPS_F 1e-5f
#define NEGMAX -3.4028235e38f
#define EPB 8      // edges per edge-block

typedef __attribute__((ext_vector_type(2))) float v2f;

// R27: R26 (412.7us best) + wave-uniform tail-slot predication in the edge
// kernel. s = t>>7 is wave-uniform, so validity vA = g*8+s < u and
// vB = g*8+s+4 < u (vB => vA) are wave-uniform -> whole waves branch into
// {joint | A-only (half FMAs) | skip} for B1/B2/B3/B4/B6/B7 at zero
// divergence cost. Invalid slots: w4 written as zeros; afeat features
// unwritten (logit overridden to NEGMAX before use). Stage A unchanged
// (cooperative). Valid-slot arithmetic bit-identical. Partial tail blocks
// (~2048 of 5250 active, ~4.5/8 valid) drop ~40% of B-phase work.
// Pre-commit: edge gain < 8us -> plateau next round.

// ---------------------------------------------------------------------------
// k_qk: blocks [0, N/2): query pair (LN + Wq + mask prep for n0,n1).
//       blocks [N/2, N): key pair (Wk for n0,n1).   (identical to R26)
// ---------------------------------------------------------------------------
__global__ __launch_bounds__(128) void k_qk(
    const float* __restrict__ qs_in, const float* __restrict__ qv_in,
    const float* __restrict__ ks_in, const float* __restrict__ kv_in,
    const float* __restrict__ Wq_s, const float* __restrict__ Wq_v, const float* __restrict__ bq,
    const float* __restrict__ Wk_s, const float* __restrict__ Wk_v, const float* __restrict__ bk,
    const float* __restrict__ ln_gs, const float* __restrict__ ln_bs, const float* __restrict__ ln_gv,
    const int* __restrict__ mask,
    float4* __restrict__ q4, float4* __restrict__ k4,
    float* __restrict__ skip_s, float* __restrict__ skip_v,
    int* __restrict__ kidx, int* __restrict__ ucnt,
    float* __restrict__ attn_raw, float* __restrict__ mbuf)
{
    const int t = threadIdx.x;
    __shared__ __align__(16) float raw0[D_F*3], raw1[D_F*3];
    __shared__ float4 sv0[D_F], sv1[D_F];
    __shared__ float red[12];
    if (blockIdx.x < N_Q/2) {
        const int n0 = blockIdx.x*2, n1 = n0 + 1;
        // ---- fused k_prep: wave0 -> n0, wave1 -> n1 ----
        {
            int which = t >> 6;
            int nn = n0 + which;
            int tt = t & 63;
            const int k = tt & 31;
            int mk = (tt < 32) ? mask[nn*K_E + k] : 0;
            unsigned long long bal = __ballot(mk != 0);
            int u = (int)__popcll(bal);
            if (tt < 32 && mk) {
                int pos = (int)__popcll(bal & ((1ull << k) - 1ull));
                kidx[nn*K_E + pos] = k;
            }
            if (tt == 0) ucnt[nn] = u;
            if (mask[nn*K_E + k] == 0) {
                int hb = (tt >> 5) * 4;
                #pragma unroll
                for (int hh = 0; hh < 4; ++hh)
                    attn_raw[(size_t)(hb + hh)*(N_Q*K_E) + nn*K_E + k] = NEGMAX;
            }
            int gU = (u + 7) >> 3;
            if (tt < 16) {
                for (int g2 = gU; g2 < 4; ++g2)
                    mbuf[(nn*4 + g2)*16 + tt] = (tt < 8) ? NEGMAX : 0.f;
            }
        }
        // ---- LN for both n ----
        float sval0 = qs_in[n0*D_F + t];
        float sval1 = qs_in[n1*D_F + t];
        float ssqp0 = 0.f, ssqp1 = 0.f;
        if (t < 96) {
            float4 rv0 = ((const float4*)(qv_in + (size_t)n0*D_F*3))[t];
            float4 rv1 = ((const float4*)(qv_in + (size_t)n1*D_F*3))[t];
            ((float4*)raw0)[t] = rv0;
            ((float4*)raw1)[t] = rv1;
            ssqp0 = rv0.x*rv0.x + rv0.y*rv0.y + rv0.z*rv0.z + rv0.w*rv0.w;
            ssqp1 = rv1.x*rv1.x + rv1.y*rv1.y + rv1.z*rv1.z + rv1.w*rv1.w;
        }
        float r0 = sval0, r1 = sval0*sval0, r2 = ssqp0;
        float r3 = sval1, r4 = sval1*sval1, r5 = ssqp1;
        #pragma unroll
        for (int m = 1; m < 64; m <<= 1) {
            r0 += __shfl_xor(r0, m);
            r1 += __shfl_xor(r1, m);
            r2 += __shfl_xor(r2, m);
            r3 += __shfl_xor(r3, m);
            r4 += __shfl_xor(r4, m);
            r5 += __shfl_xor(r5, m);
        }
        if ((t & 63) == 0) {
            int w = t >> 6;
            red[w*6+0] = r0; red[w*6+1] = r1; red[w*6+2] = r2;
            red[w*6+3] = r3; red[w*6+4] = r4; red[w*6+5] = r5;
        }
        __syncthreads();
        float tS0 = red[0]+red[6],  tS20 = red[1]+red[7],  tQ0 = red[2]+red[8];
        float tS1 = red[3]+red[9],  tS21 = red[4]+red[10], tQ1 = red[5]+red[11];
        float gs = ln_gs[t], bs = ln_bs[t], gv = ln_gv[t];
        float mu0 = tS0 * (1.f/D_F);
        float var0 = fmaxf(tS20*(1.f/D_F) - mu0*mu0, 0.f);
        float rstd0 = rsqrtf(var0 + EPS_F);
        float rrms0 = rsqrtf(tQ0*(1.f/D_F) + EPS_F);
        float a0s = (sval0 - mu0)*rstd0*gs + bs;
        skip_s[n0*D_F + t] = a0s;
        float b00 = raw0[t*3+0]*rrms0*gv;
        float b01 = raw0[t*3+1]*rrms0*gv;
        float b02 = raw0[t*3+2]*rrms0*gv;
        skip_v[(n0*D_F + t)*3 + 0] = b00;
        skip_v[(n0*D_F + t)*3 + 1] = b01;
        skip_v[(n0*D_F + t)*3 + 2] = b02;
        sv0[t] = make_float4(b00, b01, b02, a0s);
        float mu1 = tS1 * (1.f/D_F);
        float var1 = fmaxf(tS21*(1.f/D_F) - mu1*mu1, 0.f);
        float rstd1 = rsqrtf(var1 + EPS_F);
        float rrms1 = rsqrtf(tQ1*(1.f/D_F) + EPS_F);
        float a1s = (sval1 - mu1)*rstd1*gs + bs;
        skip_s[n1*D_F + t] = a1s;
        float b10 = raw1[t*3+0]*rrms1*gv;
        float b11 = raw1[t*3+1]*rrms1*gv;
        float b12 = raw1[t*3+2]*rrms1*gv;
        skip_v[(n1*D_F + t)*3 + 0] = b10;
        skip_v[(n1*D_F + t)*3 + 1] = b11;
        skip_v[(n1*D_F + t)*3 + 2] = b12;
        sv1[t] = make_float4(b10, b11, b12, a1s);
        __syncthreads();
        float bq_r = bq[t];
        v2f a01_0 = (v2f){0.f, 0.f}, a2s_0 = (v2f){0.f, bq_r};
        v2f a01_1 = (v2f){0.f, 0.f}, a2s_1 = (v2f){0.f, bq_r};
        #pragma unroll 4
        for (int i = 0; i < D_F; ++i) {
            float4 p0 = sv0[i];
            float4 p1 = sv1[i];
            float ws = Wq_s[i*D_F + t];
            float wv = Wq_v[i*D_F + t];
            v2f wvv = (v2f){wv, wv};
            v2f wvs = (v2f){wv, ws};
            a01_0 += (v2f){p0.x, p0.y} * wvv;
            a2s_0 += (v2f){p0.z, p0.w} * wvs;
            a01_1 += (v2f){p1.x, p1.y} * wvv;
            a2s_1 += (v2f){p1.z, p1.w} * wvs;
        }
        q4[n0*D_F + t] = make_float4(a01_0.x, a01_0.y, a2s_0.x, a2s_0.y);
        q4[n1*D_F + t] = make_float4(a01_1.x, a01_1.y, a2s_1.x, a2s_1.y);
    } else {
        const int nb = blockIdx.x - N_Q/2;
        const int n0 = nb*2, n1 = n0 + 1;
        float sval0 = ks_in[n0*D_F + t];
        float sval1 = ks_in[n1*D_F + t];
        if (t < 96) {
            ((float4*)raw0)[t] = ((const float4*)(kv_in + (size_t)n0*D_F*3))[t];
            ((float4*)raw1)[t] = ((const float4*)(kv_in + (size_t)n1*D_F*3))[t];
        }
        __syncthreads();
        sv0[t] = make_float4(raw0[t*3+0], raw0[t*3+1], raw0[t*3+2], sval0);
        sv1[t] = make_float4(raw1[t*3+0], raw1[t*3+1], raw1[t*3+2], sval1);
        __syncthreads();
        float bk_r = bk[t];
        v2f a01_0 = (v2f){0.f, 0.f}, a2s_0 = (v2f){0.f, bk_r};
        v2f a01_1 = (v2f){0.f, 0.f}, a2s_1 = (v2f){0.f, bk_r};
        #pragma unroll 4
        for (int i = 0; i < D_F; ++i) {
            float4 p0 = sv0[i];
            float4 p1 = sv1[i];
            float ws = Wk_s[i*D_F + t];
            float wv = Wk_v[i*D_F + t];
            v2f wvv = (v2f){wv, wv};
            v2f wvs = (v2f){wv, ws};
            a01_0 += (v2f){p0.x, p0.y} * wvv;
            a2s_0 += (v2f){p0.z, p0.w} * wvs;
            a01_1 += (v2f){p1.x, p1.y} * wvv;
            a2s_1 += (v2f){p1.z, p1.w} * wvs;
        }
        k4[n0*D_F + t] = make_float4(a01_0.x, a01_0.y, a2s_0.x, a2s_0.y);
        k4[n1*D_F + t] = make_float4(a01_1.x, a01_1.y, a2s_1.x, a2s_1.y);
    }
}

// ---------------------------------------------------------------------------
// k_edge_flash: R26 pipeline + wave-uniform validity predication.
// ---------------------------------------------------------------------------
__global__ __launch_bounds__(512, 6) void k_edge_flash(
    const float4* __restrict__ q4, const float4* __restrict__ k4,
    const float* __restrict__ eis, const float* __restrict__ eiv,
    const float* __restrict__ eemb,
    const int* __restrict__ knn,
    const int* __restrict__ kidx, const int* __restrict__ ucnt,
    const float* __restrict__ Wqk_s, const float* __restrict__ Wqk_v, const float* __restrict__ bqk,
    const float* __restrict__ Wdtp, const float* __restrict__ bdtp,
    const float* __restrict__ Wagv_s, const float* __restrict__ bagv, const float* __restrict__ Wagv_v,
    const float* __restrict__ Wattn, const float* __restrict__ lna_g, const float* __restrict__ lna_b,
    const float* __restrict__ Wval_s, const float* __restrict__ Wval_v, const float* __restrict__ bval,
    float4* __restrict__ pbuf, float* __restrict__ mbuf, float* __restrict__ attn_raw)
{
    const int n = blockIdx.x & (N_Q - 1);   // g-major: XCD = n%8 per plane
    const int g = blockIdx.x >> 11;
    const int base = n*K_E;
    const int u = ucnt[n];
    if ((g << 3) >= u) return;         // dead group: mbuf prefilled in k_qk

    const int t = threadIdx.x;
    const int s = t >> 7, c = t & 127, h = (t >> 4) & 7, o = t & 15;
    const int rot2 = h * 2;

    __shared__ float4 ch[EPB*256];     // 32 KB (stage-A ee aliased here)
    __shared__ float4 w4[EPB*128];     // 16 KB; reused as partial-combine stage
    __shared__ float  afeat[EPB*8*17]; // 4.25 KB: 16 feats + logit col 16
    __shared__ float  mred[16];        // Mg[8], deng[8]

    // stage A: ee gather (compacted, transposed, aliased into ch) + w GEMM
    {
        float* ee = (float*)ch;        // [128][8] floats = 4 KB
        {
            int idx = t; int m = idx & 7, i = idx >> 3;
            int jj = (g<<3) + m; jj = (jj < u) ? jj : (u-1);
            int e = base + kidx[base + jj];
            ee[i*EPB+m] = eemb[(size_t)e*D_F + i];
        }
        {
            int idx = t + 512; int m = idx & 7, i = idx >> 3;
            int jj = (g<<3) + m; jj = (jj < u) ? jj : (u-1);
            int e = base + kidx[base + jj];
            ee[i*EPB+m] = eemb[(size_t)e*D_F + i];
        }
        __syncthreads();
        float b = bdtp[t];
        v2f acc2[4];
        #pragma unroll
        for (int j = 0; j < 4; ++j) acc2[j] = (v2f){b, b};
        const float4* ee4 = (const float4*)ch;
        #pragma unroll 2
        for (int i = 0; i < D_F; ++i) {
            float wv = Wdtp[i*512 + t];
            v2f wv2 = (v2f){wv, wv};
            float4 e0 = ee4[i*2];      // ds_read_b128, broadcast conflict-free
            float4 e1 = ee4[i*2+1];
            acc2[0] += (v2f){e0.x, e0.y} * wv2;
            acc2[1] += (v2f){e0.z, e0.w} * wv2;
            acc2[2] += (v2f){e1.x, e1.y} * wv2;
            acc2[3] += (v2f){e1.z, e1.w} * wv2;
        }
        __syncthreads();               // all ee reads done -> ch reusable
        float* w4f = (float*)w4;
        const int chn = t & 127, sel = t >> 7;
        #pragma unroll
        for (int m = 0; m < EPB; ++m)
            w4f[(m*128 + chn)*4 + sel] = acc2[m >> 1][m & 1];
    }

    const int mA = s, mB = s + 4;
    const bool vA = ((g<<3) + mA) < u;     // wave-uniform (s uniform per wave)
    const bool vB = ((g<<3) + mB) < u;     // vB => vA
    int jA = (g<<3) + mA; jA = (jA < u) ? jA : (u-1);
    int jB = (g<<3) + mB; jB = (jB < u) ? jB : (u-1);
    const int eA = base + kidx[base + jA];
    const int eB = base + kidx[base + jB];

    const float esA = eis[eA], esB = eis[eB];
    const float evAx = eiv[eA*3+0], evAy = eiv[eA*3+1], evAz = eiv[eA*3+2];
    const float evBx = eiv[eB*3+0], evBy = eiv[eB*3+1], evBz = eiv[eB*3+2];

    // B1: dtp1 straight from global (predicated per edge)
    if (vA) {
        float4 q  = q4[(size_t)n*D_F + c];
        const int hp = c >> 5, jc = c & 31;
        const int pos0 = hp*32 + ((jc + 2*hp) & 31);
        const int pos1 = (hp+4)*32 + ((jc + 2*(hp+4)) & 31);
        float4 kA = k4[(size_t)knn[eA]*D_F + c];
        ch[mA*256 + pos0] = make_float4(q.w*kA.x, q.w*kA.y, q.w*kA.z, q.w*kA.w);
        ch[mA*256 + pos1] = make_float4(kA.w*q.x, kA.w*q.y, kA.w*q.z,
                                        q.x*kA.x + q.y*kA.y + q.z*kA.z);
        if (vB) {
            float4 kB = k4[(size_t)knn[eB]*D_F + c];
            ch[mB*256 + pos0] = make_float4(q.w*kB.x, q.w*kB.y, q.w*kB.z, q.w*kB.w);
            ch[mB*256 + pos1] = make_float4(kB.w*q.x, kB.w*q.y, kB.w*q.z,
                                            q.x*kB.x + q.y*kB.y + q.z*kB.z);
        }
    }
    __syncthreads();

    const int chA = mA*256 + h*32, chB = mB*256 + h*32;

    // B2: Wqk — packed, predicated {joint | A-only | skip}
    float pAs=0.f, pA0=0.f, pA1=0.f, pA2=0.f, pBs=0.f, pB0=0.f, pB1=0.f, pB2=0.f;
    if (vB) {
        const float bqk_r = bqk[o];
        v2f a01A = (v2f){0.f, 0.f}, a2sA = (v2f){0.f, bqk_r};
        v2f a01B = (v2f){0.f, 0.f}, a2sB = (v2f){0.f, bqk_r};
        #pragma unroll 4
        for (int i = 0; i < 32; ++i) {
            int ph = (i + rot2) & 31;
            float4 cA = ch[chA + ph];
            float4 cB = ch[chB + ph];
            float ws = Wqk_s[i*16 + o];
            float wv = Wqk_v[i*16 + o];
            v2f wvv = (v2f){wv, wv};
            v2f wvs = (v2f){wv, ws};
            a01A += (v2f){cA.x, cA.y} * wvv;
            a2sA += (v2f){cA.z, cA.w} * wvs;
            a01B += (v2f){cB.x, cB.y} * wvv;
            a2sB += (v2f){cB.z, cB.w} * wvs;
        }
        pA0 = a01A.x; pA1 = a01A.y; pA2 = a2sA.x; pAs = a2sA.y;
        pB0 = a01B.x; pB1 = a01B.y; pB2 = a2sB.x; pBs = a2sB.y;
    } else if (vA) {
        const float bqk_r = bqk[o];
        v2f a01A = (v2f){0.f, 0.f}, a2sA = (v2f){0.f, bqk_r};
        #pragma unroll 4
        for (int i = 0; i < 32; ++i) {
            int ph = (i + rot2) & 31;
            float4 cA = ch[chA + ph];
            float ws = Wqk_s[i*16 + o];
            float wv = Wqk_v[i*16 + o];
            a01A += (v2f){cA.x, cA.y} * (v2f){wv, wv};
            a2sA += (v2f){cA.z, cA.w} * (v2f){wv, ws};
        }
        pA0 = a01A.x; pA1 = a01A.y; pA2 = a2sA.x; pAs = a2sA.y;
    }
    __syncthreads();

    const int posA = h*32 + ((o + rot2) & 31);
    const int posB = h*32 + ((o + 16 + rot2) & 31);

    // B3: dtp2 (weighted), predicated per edge
    if (vA) {
        float4 wA = w4[mA*128 + c];
        ch[mA*256 + posA] = make_float4(pAs*evAx*wA.z, pAs*evAy*wA.z, pAs*evAz*wA.z, pAs*esA*wA.x);
        float dA = pA0*evAx + pA1*evAy + pA2*evAz;
        ch[mA*256 + posB] = make_float4(esA*pA0*wA.w, esA*pA1*wA.w, esA*pA2*wA.w, dA*wA.y);
    }
    if (vB) {
        float4 wB = w4[mB*128 + c];
        ch[mB*256 + posA] = make_float4(pBs*evBx*wB.z, pBs*evBy*wB.z, pBs*evBz*wB.z, pBs*esB*wB.x);
        float dB = pB0*evBx + pB1*evBy + pB2*evBz;
        ch[mB*256 + posB] = make_float4(esB*pB0*wB.w, esB*pB1*wB.w, esB*pB2*wB.w, dB*wB.y);
    }
    __syncthreads();

    // B4: Wagv — packed, predicated {joint | A-only | skip}
    float gtA=0.f, vlA=0.f, vA0=0.f, vA1=0.f, vA2=0.f;
    float gtB=0.f, vlB=0.f, vB0=0.f, vB1=0.f, vB2=0.f;
    if (vB) {
        const float bag0 = bagv[h*48 + o];
        const float bag1 = bagv[h*48 + 16 + o];
        const float bag2 = bagv[h*48 + 32 + o];
        v2f v01A = (v2f){0.f, 0.f}, v2atA = (v2f){0.f, bag0}, gtvlA = (v2f){bag1, bag2};
        v2f v01B = (v2f){0.f, 0.f}, v2atB = (v2f){0.f, bag0}, gtvlB = (v2f){bag1, bag2};
        #pragma unroll 4
        for (int i = 0; i < 32; ++i) {
            int ph = (i + rot2) & 31;
            float4 cA = ch[chA + ph];
            float4 cB = ch[chB + ph];
            const float* wrow = &Wagv_s[(h*32+i)*48];
            float w0 = wrow[o], w1 = wrow[16+o], w2 = wrow[32+o];
            float wv = Wagv_v[(h*32+i)*16 + o];
            v2f wvv = (v2f){wv, wv};
            v2f wv0 = (v2f){wv, w0};
            v2f w12 = (v2f){w1, w2};
            v01A  += (v2f){cA.x, cA.y} * wvv;
            v2atA += (v2f){cA.z, cA.w} * wv0;
            gtvlA += (v2f){cA.w, cA.w} * w12;
            v01B  += (v2f){cB.x, cB.y} * wvv;
            v2atB += (v2f){cB.z, cB.w} * wv0;
            gtvlB += (v2f){cB.w, cB.w} * w12;
        }
        vA0 = v01A.x; vA1 = v01A.y; vA2 = v2atA.x;
        gtA = gtvlA.x; vlA = gtvlA.y;
        vB0 = v01B.x; vB1 = v01B.y; vB2 = v2atB.x;
        gtB = gtvlB.x; vlB = gtvlB.y;
        afeat[(mA*8 + h)*17 + o] = v2atA.y;
        afeat[(mB*8 + h)*17 + o] = v2atB.y;
    } else if (vA) {
        const float bag0 = bagv[h*48 + o];
        const float bag1 = bagv[h*48 + 16 + o];
        const float bag2 = bagv[h*48 + 32 + o];
        v2f v01A = (v2f){0.f, 0.f}, v2atA = (v2f){0.f, bag0}, gtvlA = (v2f){bag1, bag2};
        #pragma unroll 4
        for (int i = 0; i < 32; ++i) {
            int ph = (i + rot2) & 31;
            float4 cA = ch[chA + ph];
            const float* wrow = &Wagv_s[(h*32+i)*48];
            float w0 = wrow[o], w1 = wrow[16+o], w2 = wrow[32+o];
            float wv = Wagv_v[(h*32+i)*16 + o];
            v01A  += (v2f){cA.x, cA.y} * (v2f){wv, wv};
            v2atA += (v2f){cA.z, cA.w} * (v2f){wv, w0};
            gtvlA += (v2f){cA.w, cA.w} * (v2f){w1, w2};
        }
        vA0 = v01A.x; vA1 = v01A.y; vA2 = v2atA.x;
        gtA = gtvlA.x; vlA = gtvlA.y;
        afeat[(mA*8 + h)*17 + o] = v2atA.y;
    }
    __syncthreads();

    // B5: logits (wave 0: 8 slots x 8 heads) + group max/den via shuffles
    if (t < EPB*H_N) {
        int m2 = t >> 3, h2 = t & 7;
        const float* afr = &afeat[(m2*8 + h2)*17];
        float mu = 0.f;
        #pragma unroll 4
        for (int d2 = 0; d2 < DH_N; ++d2) mu += afr[d2];
        mu *= (1.f/DH_N);
        float var = 0.f;
        #pragma unroll 4
        for (int d2 = 0; d2 < DH_N; ++d2) { float dd = afr[d2]-mu; var += dd*dd; }
        var *= (1.f/DH_N);
        float rstd = rsqrtf(var + EPS_F);
        float logit = 0.f;
        #pragma unroll 4
        for (int d2 = 0; d2 < DH_N; ++d2) {
            float xn = (afr[d2]-mu)*rstd*lna_g[d2] + lna_b[d2];
            logit += xn*Wattn[d2];
        }
        int jj = (g<<3) + m2;
        bool vok = jj < u;
        if (vok) {
            int kor = kidx[base + jj];
            attn_raw[h2*(N_Q*K_E) + n*K_E + kor] = logit;
        } else {
            logit = NEGMAX;            // invalid slot (garbage feats discarded)
        }
        afeat[(m2*8 + h2)*17 + 16] = logit;
        float mx = logit;
        mx = fmaxf(mx, __shfl_xor(mx, 8));
        mx = fmaxf(mx, __shfl_xor(mx, 16));
        mx = fmaxf(mx, __shfl_xor(mx, 32));
        float ex = expf(logit - mx);
        ex += __shfl_xor(ex, 8);
        ex += __shfl_xor(ex, 16);
        ex += __shfl_xor(ex, 32);
        if (m2 == 0) { mred[h2] = mx; mred[8 + h2] = ex; }
    }
    // gating (register-only; zero-inited for invalid slots)
    float sactA = vlA / (1.f + expf(-vlA));
    float gA = 1.f / (1.f + expf(-gtA));
    float qA0 = vA0*gA, qA1 = vA1*gA, qA2 = vA2*gA;
    float sactB = vlB / (1.f + expf(-vlB));
    float gB = 1.f / (1.f + expf(-gtB));
    float qB0 = vB0*gB, qB1 = vB1*gB, qB2 = vB2*gB;

    // B6: dtp3, predicated per edge
    if (vA) {
        ch[mA*256 + posA] = make_float4(sactA*evAx, sactA*evAy, sactA*evAz, sactA*esA);
        float dA = qA0*evAx + qA1*evAy + qA2*evAz;
        ch[mA*256 + posB] = make_float4(esA*qA0, esA*qA1, esA*qA2, dA);
    }
    if (vB) {
        ch[mB*256 + posA] = make_float4(sactB*evBx, sactB*evBy, sactB*evBz, sactB*esB);
        float dB = qB0*evBx + qB1*evBy + qB2*evBz;
        ch[mB*256 + posB] = make_float4(esB*qB0, esB*qB1, esB*qB2, dB);
    }
    __syncthreads();

    // B7: Wval — packed, predicated; weight by exp(logit - Mg), stage in w4
    if (vB) {
        const float bval_r = bval[o];
        v2f u01A = (v2f){0.f, 0.f}, u2sA = (v2f){0.f, bval_r};
        v2f u01B = (v2f){0.f, 0.f}, u2sB = (v2f){0.f, bval_r};
        #pragma unroll 4
        for (int i = 0; i < 32; ++i) {
            int ph = (i + rot2) & 31;
            float4 cA = ch[chA + ph];
            float4 cB = ch[chB + ph];
            float ws = Wval_s[i*16 + o];
            float wv = Wval_v[i*16 + o];
            v2f wvv = (v2f){wv, wv};
            v2f wvs = (v2f){wv, ws};
            u01A += (v2f){cA.x, cA.y} * wvv;
            u2sA += (v2f){cA.z, cA.w} * wvs;
            u01B += (v2f){cB.x, cB.y} * wvv;
            u2sB += (v2f){cB.z, cB.w} * wvs;
        }
        float lA = afeat[(mA*8 + h)*17 + 16];
        float lB = afeat[(mB*8 + h)*17 + 16];
        float Mg = mred[h];
        float wgA = expf(lA - Mg);
        float wgB = expf(lB - Mg);
        w4[s*128 + c] = make_float4(wgA*u01A.x + wgB*u01B.x,
                                    wgA*u01A.y + wgB*u01B.y,
                                    wgA*u2sA.x + wgB*u2sB.x,
                                    wgA*u2sA.y + wgB*u2sB.y);
    } else if (vA) {
        const float bval_r = bval[o];
        v2f u01A = (v2f){0.f, 0.f}, u2sA = (v2f){0.f, bval_r};
        #pragma unroll 4
        for (int i = 0; i < 32; ++i) {
            int ph = (i + rot2) & 31;
            float4 cA = ch[chA + ph];
            float ws = Wval_s[i*16 + o];
            float wv = Wval_v[i*16 + o];
            u01A += (v2f){cA.x, cA.y} * (v2f){wv, wv};
            u2sA += (v2f){cA.z, cA.w} * (v2f){wv, ws};
        }
        float lA = afeat[(mA*8 + h)*17 + 16];
        float Mg = mred[h];
        float wgA = expf(lA - Mg);
        w4[s*128 + c] = make_float4(wgA*u01A.x, wgA*u01A.y,
                                    wgA*u2sA.x, wgA*u2sA.y);
    } else {
        w4[s*128 + c] = make_float4(0.f, 0.f, 0.f, 0.f);
    }
    __syncthreads();

    // tail: combine 4 s-slots -> one partial float4 per channel; emit Mg/deng
    if (t < 128) {
        float4 a = w4[t], b4 = w4[128 + t], c4 = w4[256 + t], d4 = w4[384 + t];
        pbuf[((size_t)(n*4 + g))*D_F + t] =
            make_float4(a.x + b4.x + c4.x + d4.x, a.y + b4.y + c4.y + d4.y,
                        a.z + b4.z + c4.z + d4.z, a.w + b4.w + c4.w + d4.w);
    } else if (t < 144) {
        mbuf[(n*4 + g)*16 + (t - 128)] = mred[t - 128];
    }
}

// ---------------------------------------------------------------------------
// k_finish: FOUR n per block (128 threads), packed-FP32 Wo GEMM; each Wo
// weight load feeds all 4 n.   (identical to R26)
// ---------------------------------------------------------------------------
__global__ __launch_bounds__(128) void k_finish(
    const float4* __restrict__ pbuf, const float* __restrict__ mbuf,
    float* __restrict__ attn_out,     // in: raw logits, out: probabilities
    const float* __restrict__ skip_s, const float* __restrict__ skip_v,
    const float* __restrict__ Wo_s, const float* __restrict__ Wo_v, const float* __restrict__ bo,
    float* __restrict__ out0, float* __restrict__ out1)
{
    const int n0 = blockIdx.x*4, t = threadIdx.x;
    __shared__ float MsDn[64];            // [which*16 + (M 0-7 | Dn 8-15)]
    __shared__ float4 xsh[4*D_F];         // 8 KB
    // F1: per-head global max/den for 4 n (all 128 threads)
    {
        int which = t >> 5, tt = t & 31;
        int nn = n0 + which;
        int h3 = tt >> 2, g3 = tt & 3;
        float mg = mbuf[(nn*4 + g3)*16 + h3];
        float dg = mbuf[(nn*4 + g3)*16 + 8 + h3];
        float mx = mg;
        mx = fmaxf(mx, __shfl_xor(mx, 1));
        mx = fmaxf(mx, __shfl_xor(mx, 2));
        float dsc = dg * expf(mg - mx);   // dead group: 0 * 0
        dsc += __shfl_xor(dsc, 1);
        dsc += __shfl_xor(dsc, 2);
        if (g3 == 0) { MsDn[which*16 + h3] = mx; MsDn[which*16 + 8 + h3] = dsc; }
    }
    __syncthreads();
    const int h = t >> 4, o = t & 15;
    // F2: combine group partials for all 4 n; probs in place
    #pragma unroll
    for (int w = 0; w < 4; ++w) {
        int nn = n0 + w;
        const float M = MsDn[w*16 + h];
        const float rden = 1.f / MsDn[w*16 + 8 + h];
        float4 acc = make_float4(0.f, 0.f, 0.f, 0.f);
        #pragma unroll
        for (int gg = 0; gg < 4; ++gg) {
            float mg = mbuf[(nn*4 + gg)*16 + h];
            if (mg > -1e37f) {            // skip dead groups (pbuf unwritten)
                float4 pv = pbuf[((size_t)(nn*4 + gg))*D_F + t];
                float sf = expf(mg - M) * rden;
                acc.x += pv.x*sf; acc.y += pv.y*sf; acc.z += pv.z*sf; acc.w += pv.w*sf;
            }
        }
        xsh[w*D_F + t] = acc;
        #pragma unroll
        for (int kk = 0; kk < 2; ++kk) {
            size_t idx = (size_t)h*(N_Q*K_E) + (size_t)nn*K_E + (o + kk*16);
            attn_out[idx] = expf(attn_out[idx] - M) * rden;
        }
    }
    __syncthreads();
    // F3: Wo GEMM, one weight load -> 4 n, packed pairs (static unroll)
    float bo_r = bo[t];
    v2f xy0 = (v2f){0.f, 0.f}, zs0 = (v2f){0.f, bo_r};
    v2f xy1 = (v2f){0.f, 0.f}, zs1 = (v2f){0.f, bo_r};
    v2f xy2 = (v2f){0.f, 0.f}, zs2 = (v2f){0.f, bo_r};
    v2f xy3 = (v2f){0.f, 0.f}, zs3 = (v2f){0.f, bo_r};
    #pragma unroll 4
    for (int i = 0; i < D_F; ++i) {
        float ws = Wo_s[i*D_F + t];
        float wv = Wo_v[i*D_F + t];
        v2f wvv = (v2f){wv, wv};
        v2f wvs = (v2f){wv, ws};
        float4 x0 = xsh[i];
        float4 x1 = xsh[D_F + i];
        float4 x2 = xsh[2*D_F + i];
        float4 x3 = xsh[3*D_F + i];
        xy0 += (v2f){x0.x, x0.y} * wvv;  zs0 += (v2f){x0.z, x0.w} * wvs;
        xy1 += (v2f){x1.x, x1.y} * wvv;  zs1 += (v2f){x1.z, x1.w} * wvs;
        xy2 += (v2f){x2.x, x2.y} * wvv;  zs2 += (v2f){x2.z, x2.w} * wvs;
        xy3 += (v2f){x3.x, x3.y} * wvv;  zs3 += (v2f){x3.z, x3.w} * wvs;
    }
    {
        int nn = n0;
        out0[nn*D_F + t] = zs0.y + skip_s[nn*D_F + t];
        out1[(nn*D_F + t)*3 + 0] = xy0.x + skip_v[(nn*D_F + t)*3 + 0];
        out1[(nn*D_F + t)*3 + 1] = xy0.y + skip_v[(nn*D_F + t)*3 + 1];
        out1[(nn*D_F + t)*3 + 2] = zs0.x + skip_v[(nn*D_F + t)*3 + 2];
    }
    {
        int nn = n0 + 1;
        out0[nn*D_F + t] = zs1.y + skip_s[nn*D_F + t];
        out1[(nn*D_F + t)*3 + 0] = xy1.x + skip_v[(nn*D_F + t)*3 + 0];
        out1[(nn*D_F + t)*3 + 1] = xy1.y + skip_v[(nn*D_F + t)*3 + 1];
        out1[(nn*D_F + t)*3 + 2] = zs1.x + skip_v[(nn*D_F + t)*3 + 2];
    }
    {
        int nn = n0 + 2;
        out0[nn*D_F + t] = zs2.y + skip_s[nn*D_F + t];
        out1[(nn*D_F + t)*3 + 0] = xy2.x + skip_v[(nn*D_F + t)*3 + 0];
        out1[(nn*D_F + t)*3 + 1] = xy2.y + skip_v[(nn*D_F + t)*3 + 1];
        out1[(nn*D_F + t)*3 + 2] = zs2.x + skip_v[(nn*D_F + t)*3 + 2];
    }
    {
        int nn = n0 + 3;
        out0[nn*D_F + t] = zs3.y + skip_s[nn*D_F + t];
        out1[(nn*D_F + t)*3 + 0] = xy3.x + skip_v[(nn*D_F + t)*3 + 0];
        out1[(nn*D_F + t)*3 + 1] = xy3.y + skip_v[(nn*D_F + t)*3 + 1];
        out1[(nn*D_F + t)*3 + 2] = zs3.x + skip_v[(nn*D_F + t)*3 + 2];
    }
}

// ---------------------------------------------------------------------------
extern "C" void kernel_launch(void* const* d_in, const int* in_sizes, int n_in,
                              void* d_out, int out_size, void* d_ws, size_t ws_size,
                              hipStream_t stream)
{
    (void)in_sizes; (void)n_in; (void)out_size; (void)ws_size;

    const float* query_s = (const float*)d_in[0];
    const float* query_v = (const float*)d_in[1];
    const float* key_s   = (const float*)d_in[2];
    const float* key_v   = (const float*)d_in[3];
    const float* eis     = (const float*)d_in[4];
    const float* eiv     = (const float*)d_in[5];
    const float* eemb    = (const float*)d_in[6];
    const int*   mask    = (const int*)d_in[7];
    const int*   knn     = (const int*)d_in[8];
    const float* Wq_s    = (const float*)d_in[9];
    const float* Wq_v    = (const float*)d_in[10];
    const float* bq      = (const float*)d_in[11];
    const float* Wk_s    = (const float*)d_in[12];
    const float* Wk_v    = (const float*)d_in[13];
    const float* bk      = (const float*)d_in[14];
    const float* Wqk_s   = (const float*)d_in[15];
    const float* Wqk_v   = (const float*)d_in[16];
    const float* bqk     = (const float*)d_in[17];
    const float* Wdtp    = (const float*)d_in[18];
    const float* bdtp    = (const float*)d_in[19];
    const float* Wagv_s  = (const float*)d_in[20];
    const float* bagv    = (const float*)d_in[21];
    const float* Wagv_v  = (const float*)d_in[22];
    const float* Wattn   = (const float*)d_in[23];
    const float* Wval_s  = (const float*)d_in[24];
    const float* Wval_v  = (const float*)d_in[25];
    const float* bval    = (const float*)d_in[26];
    const float* Wo_s    = (const float*)d_in[27];
    const float* Wo_v    = (const float*)d_in[28];
    const float* bo      = (const float*)d_in[29];
    const float* ln_gs   = (const float*)d_in[30];
    const float* ln_bs   = (const float*)d_in[31];
    const float* ln_gv   = (const float*)d_in[32];
    const float* lna_g   = (const float*)d_in[33];
    const float* lna_b   = (const float*)d_in[34];

    float* out      = (float*)d_out;
    float* out_s    = out;
    float* out_v    = out + N_Q*D_F;
    float* out_attn = out + N_Q*D_F*4;

    float* ws = (float*)d_ws;
    float4* q4     = (float4*)ws;                      // N*128 f4 = 4 MB
    float4* k4     = q4 + N_Q*D_F;                     // 4 MB
    float*  skip_s = (float*)(k4 + N_Q*D_F);           // 1 MB
    float*  skip_v = skip_s + N_Q*D_F;                 // 3 MB
    float4* pbuf   = (float4*)(skip_v + N_Q*D_F*3);    // N*4*128 f4 = 16 MB
    float*  mbuf   = (float*)(pbuf + N_Q*4*D_F);       // N*4*16 f = 512 KB
    int*    kidx   = (int*)(mbuf + N_Q*4*16);          // N*K ints = 256 KB
    int*    ucnt   = kidx + N_Q*K_E;                   // N ints

    hipLaunchKernelGGL(k_qk, dim3(N_Q), dim3(D_F), 0, stream,
                       query_s, query_v, key_s, key_v,
                       Wq_s, Wq_v, bq, Wk_s, Wk_v, bk,
                       ln_gs, ln_bs, ln_gv, mask,
                       q4, k4, skip_s, skip_v,
                       kidx, ucnt, out_attn, mbuf);
    hipLaunchKernelGGL(k_edge_flash, dim3(N_Q*K_E/EPB), dim3(512), 0, stream,
                       q4, k4, eis, eiv, eemb, knn, kidx, ucnt,
                       Wqk_s, Wqk_v, bqk, Wdtp, bdtp,
                       Wagv_s, bagv, Wagv_v, Wattn, lna_g, lna_b,
                       Wval_s, Wval_v, bval,
                       pbuf, mbuf, out_attn);
    hipLaunchKernelGGL(k_finish, dim3(N_Q/4), dim3(D_F), 0, stream,
                       pbuf, mbuf, out_attn, skip_s, skip_v, Wo_s, Wo_v, bo,
                       out_s, out_v);
}